// Round 4
// baseline (348.617 us; speedup 1.0000x reference)
//
#include <hip/hip_runtime.h>
#include <math.h>

typedef unsigned short u16;
typedef unsigned int   u32;
typedef __attribute__((ext_vector_type(8))) short bf16x8;
typedef __attribute__((ext_vector_type(4))) float f32x4;

#define N_WIN 2048
#define PW    64
#define KA    40
#define MSEL  1536
#define CH    128
#define NH    4
#define GLUI  320
#define NTOK  (MSEL*KA)          // 61440
#define RPC   16384              // rows per chunk (CB mean)

__device__ __forceinline__ u16 f2b(float f) {
    u32 u = __float_as_uint(f);
    return (u16)((u + 0x7FFFu + ((u >> 16) & 1u)) >> 16);
}
__device__ __forceinline__ float b2f(u16 v) { return __uint_as_float(((u32)v) << 16); }

// ---------------- all weights fp32 -> bf16 transposed, one launch -----------
__global__ __launch_bounds__(256) void k_cvt(const float* __restrict__ qkv_w,
                                             const float* __restrict__ proj_w,
                                             const float* __restrict__ glu_w,
                                             const float* __restrict__ out_w,
                                             u16* __restrict__ wq, u16* __restrict__ wp,
                                             u16* __restrict__ wg, u16* __restrict__ wo) {
    int idx = blockIdx.x * 256 + threadIdx.x;
    if (idx < 49152) {
        int n = idx / 128, k = idx % 128;
        wq[idx] = f2b(qkv_w[k * 384 + n]);
    } else if (idx < 65536) {
        int i = idx - 49152, n = i / 128, k = i % 128;
        wp[i] = f2b(proj_w[k * 128 + n]);
    } else if (idx < 147456) {
        int i = idx - 65536, n = i / 128, k = i % 128;
        wg[i] = f2b(glu_w[k * 640 + n]);
    } else if (idx < 188416) {
        int i = idx - 147456, n = i / 320, k = i % 320;
        wo[i] = f2b(out_w[k * 128 + n]);
    }
}

// ---------------- LN1 over all 131072 rows -> d_out (float4, 2 rows/wave) ---
__global__ __launch_bounds__(256) void k_ln1(const float* __restrict__ x,
                                             const float* __restrict__ g,
                                             const float* __restrict__ b,
                                             float* __restrict__ out) {
    int wave = threadIdx.x >> 6, lane = threadIdx.x & 63;
    long row = (long)blockIdx.x * 8 + wave * 2 + (lane >> 5);
    int col = (lane & 31) * 4;
    float4 v = *(const float4*)(x + row * CH + col);
    float s  = v.x + v.y + v.z + v.w;
    float s2 = v.x * v.x + v.y * v.y + v.z * v.z + v.w * v.w;
    #pragma unroll
    for (int o = 16; o; o >>= 1) { s += __shfl_xor(s, o); s2 += __shfl_xor(s2, o); }
    float mu = s * (1.f / CH), var = s2 * (1.f / CH) - mu * mu;
    float r = rsqrtf(var + 1e-5f);
    float4 gg = *(const float4*)(g + col);
    float4 bb = *(const float4*)(b + col);
    float4 o4;
    o4.x = (v.x - mu) * r * gg.x + bb.x;
    o4.y = (v.y - mu) * r * gg.y + bb.y;
    o4.z = (v.z - mu) * r * gg.z + bb.z;
    o4.w = (v.w - mu) * r * gg.w + bb.w;
    *(float4*)(out + row * CH + col) = o4;
}

// ---------------- gather + LN2 -> s1h bf16 ----------------------------------
__global__ __launch_bounds__(256) void k_ln2a(const float* __restrict__ ln1,
                                              const float* __restrict__ g2,
                                              const float* __restrict__ b2,
                                              const int* __restrict__ iw,
                                              u16* __restrict__ s1h) {
    int wave = threadIdx.x >> 6, lane = threadIdx.x & 63;
    long row = (long)blockIdx.x * 8 + wave * 2 + (lane >> 5);   // < 61440
    int col = (lane & 31) * 4;
    int m = (int)(row / KA), r = (int)(row % KA);
    const float* src = ln1 + ((long)iw[m] * PW + r) * CH + col;
    float4 v = *(const float4*)src;
    float s  = v.x + v.y + v.z + v.w;
    float s2 = v.x * v.x + v.y * v.y + v.z * v.z + v.w * v.w;
    #pragma unroll
    for (int o = 16; o; o >>= 1) { s += __shfl_xor(s, o); s2 += __shfl_xor(s2, o); }
    float mu = s * (1.f / CH), var = s2 * (1.f / CH) - mu * mu;
    float rr = rsqrtf(var + 1e-5f);
    float4 gg = *(const float4*)(g2 + col);
    float4 bb = *(const float4*)(b2 + col);
    ushort4 o4;
    o4.x = f2b((v.x - mu) * rr * gg.x + bb.x);
    o4.y = f2b((v.y - mu) * rr * gg.y + bb.y);
    o4.z = f2b((v.z - mu) * rr * gg.z + bb.z);
    o4.w = f2b((v.w - mu) * rr * gg.w + bb.w);
    *(ushort4*)(s1h + row * CH + col) = o4;
}

// ---------------- QKV GEMM, no LDS: BM=64, BN=192, grid (960, 2) ------------
__global__ __launch_bounds__(256) void k_qkv(const u16* __restrict__ A,
                                             const u16* __restrict__ wq,
                                             const float* __restrict__ qkv_b,
                                             u16* __restrict__ qkvb) {
    int tid = threadIdx.x, wid = tid >> 6, lane = tid & 63;
    int l15 = lane & 15, lg = lane >> 4;
    long m0 = (long)blockIdx.x * 64 + wid * 16;
    int n0 = blockIdx.y * 192;
    bf16x8 af[4];
    #pragma unroll
    for (int ks = 0; ks < 4; ++ks)
        af[ks] = *(const bf16x8*)&A[(m0 + l15) * CH + ks * 32 + lg * 8];
    f32x4 acc[12] = {};
    #pragma unroll
    for (int j = 0; j < 12; ++j) {
        #pragma unroll
        for (int ks = 0; ks < 4; ++ks) {
            bf16x8 bfr = *(const bf16x8*)&wq[(long)(n0 + j * 16 + l15) * CH + ks * 32 + lg * 8];
            acc[j] = __builtin_amdgcn_mfma_f32_16x16x32_bf16(af[ks], bfr, acc[j], 0, 0, 0);
        }
    }
    #pragma unroll
    for (int j = 0; j < 12; ++j) {
        int col = n0 + j * 16 + l15;
        float bc = qkv_b[col];
        #pragma unroll
        for (int r = 0; r < 4; ++r) {
            long row = m0 + lg * 4 + r;
            qkvb[row * 384 + col] = f2b(acc[j][r] + bc);
        }
    }
}

// ---------------- per-window MFMA attention (unchanged from R3) -------------
__global__ __launch_bounds__(256) void k_attn(const u16* __restrict__ qkvb,
                                              u16* __restrict__ obuf) {
    __shared__ u16 qk[KA][392];
    __shared__ u16 vT[NH][32][72];
    int m = blockIdx.x, tid = threadIdx.x;
    int h = tid >> 6, lane = tid & 63, l15 = lane & 15, lg = lane >> 4;

    for (int i = tid; i < KA * 48; i += 256) {
        int j = i / 48, seg = i % 48;
        *(bf16x8*)&qk[j][seg * 8] = *(const bf16x8*)&qkvb[((long)m * KA + j) * 384 + seg * 8];
    }
    __syncthreads();
    for (int i = tid; i < NH * 32 * 64; i += 256) {
        int hh = i / (32 * 64), rem = i % (32 * 64), d = rem / 64, j = rem % 64;
        vT[hh][d][j] = (j < KA) ? qk[j][hh * 96 + 64 + d] : (u16)0;
    }
    __syncthreads();

    bf16x8 aq[3], bk[3];
    #pragma unroll
    for (int t = 0; t < 3; ++t) {
        int rr = t * 16 + l15; if (rr > KA - 1) rr = KA - 1;
        aq[t] = *(const bf16x8*)&qk[rr][h * 96 + lg * 8];
        bk[t] = *(const bf16x8*)&qk[rr][h * 96 + 32 + lg * 8];
    }
    f32x4 zero = {};
    f32x4 s[3][3];
    #pragma unroll
    for (int mi = 0; mi < 3; ++mi)
        #pragma unroll
        for (int ni = 0; ni < 3; ++ni)
            s[mi][ni] = __builtin_amdgcn_mfma_f32_16x16x32_bf16(aq[mi], bk[ni], zero, 0, 0, 0);

    const float scale = 0.17677669529663687f;
    float inv_[3][4];
    #pragma unroll
    for (int mi = 0; mi < 3; ++mi)
        #pragma unroll
        for (int r = 0; r < 4; ++r) {
            float v0 = s[mi][0][r] * scale;
            float v1 = s[mi][1][r] * scale;
            float v2 = (l15 >= 8) ? -1e30f : s[mi][2][r] * scale;
            float mx = fmaxf(fmaxf(v0, v1), v2);
            #pragma unroll
            for (int o = 1; o < 16; o <<= 1) mx = fmaxf(mx, __shfl_xor(mx, o));
            float e0 = __expf(v0 - mx), e1 = __expf(v1 - mx), e2 = __expf(v2 - mx);
            float sm = e0 + e1 + e2;
            #pragma unroll
            for (int o = 1; o < 16; o <<= 1) sm += __shfl_xor(sm, o);
            inv_[mi][r] = 1.f / sm;
            int row = mi * 16 + lg * 4 + r;
            if (row < KA) {
                qk[row][h * 96 + l15]      = f2b(e0);
                qk[row][h * 96 + 16 + l15] = f2b(e1);
                qk[row][h * 96 + 32 + l15] = f2b(e2);
            }
        }

    f32x4 o[3][2] = {};
    #pragma unroll
    for (int ks = 0; ks < 2; ++ks) {
        bf16x8 pa[3], vb[2];
        #pragma unroll
        for (int mi = 0; mi < 3; ++mi) {
            int rp = mi * 16 + l15; if (rp > KA - 1) rp = KA - 1;
            pa[mi] = *(const bf16x8*)&qk[rp][h * 96 + ks * 32 + lg * 8];
        }
        #pragma unroll
        for (int nf = 0; nf < 2; ++nf) vb[nf] = *(const bf16x8*)&vT[h][nf * 16 + l15][ks * 32 + lg * 8];
        #pragma unroll
        for (int mi = 0; mi < 3; ++mi)
            #pragma unroll
            for (int nf = 0; nf < 2; ++nf)
                o[mi][nf] = __builtin_amdgcn_mfma_f32_16x16x32_bf16(pa[mi], vb[nf], o[mi][nf], 0, 0, 0);
    }
    #pragma unroll
    for (int mi = 0; mi < 3; ++mi)
        #pragma unroll
        for (int nf = 0; nf < 2; ++nf)
            #pragma unroll
            for (int r = 0; r < 4; ++r) {
                int row4 = mi * 16 + lg * 4 + r;
                if (row4 < KA)
                    obuf[((long)m * KA + row4) * CH + h * 32 + nf * 16 + l15] =
                        f2b(o[mi][nf][r] * inv_[mi][r]);
            }
}

// ---------------- MEGA: proj + residual + LN2 + GLU + OUT  ------------------
// per block: 64 rows. Phase A: r1 = s1 + proj(obuf)*ls1 -> r1h + LN2 -> Al.
// Then 5 chunks of 64 GLU cols: act chunk -> Ac -> partial out-GEMM into a2.
__global__ __launch_bounds__(256) void k_mega(const u16* __restrict__ obuf,
                                              const u16* __restrict__ s1h,
                                              const u16* __restrict__ wp,
                                              const float* __restrict__ proj_b,
                                              const float* __restrict__ ls1,
                                              const float* __restrict__ g2,
                                              const float* __restrict__ b2,
                                              const u16* __restrict__ wg,
                                              const float* __restrict__ glu_b,
                                              const u16* __restrict__ wo,
                                              const float* __restrict__ out_b,
                                              u16* __restrict__ r1h,
                                              u16* __restrict__ mlph) {
    __shared__ u16 Al[64][72];
    __shared__ u16 Ac[64][72];
    int tid = threadIdx.x, wid = tid >> 6, lane = tid & 63;
    int l15 = lane & 15, lg = lane >> 4;
    long m0 = (long)blockIdx.x * 64;
    int rl0 = wid * 16;                      // this wave's local row base

    // ---- Phase A: proj GEMM (K=128) ----
    bf16x8 af[4];
    #pragma unroll
    for (int ks = 0; ks < 4; ++ks)
        af[ks] = *(const bf16x8*)&obuf[(m0 + rl0 + l15) * CH + ks * 32 + lg * 8];
    f32x4 ap[8] = {};
    #pragma unroll
    for (int j = 0; j < 8; ++j)
        #pragma unroll
        for (int ks = 0; ks < 4; ++ks) {
            bf16x8 bfr = *(const bf16x8*)&wp[(long)(j * 16 + l15) * CH + ks * 32 + lg * 8];
            ap[j] = __builtin_amdgcn_mfma_f32_16x16x32_bf16(af[ks], bfr, ap[j], 0, 0, 0);
        }
    #pragma unroll
    for (int r = 0; r < 4; ++r) {
        long row = m0 + rl0 + lg * 4 + r;
        float vals[8]; float s = 0.f, s2 = 0.f;
        #pragma unroll
        for (int j = 0; j < 8; ++j) {
            int col = j * 16 + l15;
            float v = ap[j][r] + proj_b[col];
            v = b2f(s1h[row * CH + col]) + v * ls1[col];
            vals[j] = v; s += v; s2 += v * v;
        }
        #pragma unroll
        for (int msk = 1; msk < 16; msk <<= 1) { s += __shfl_xor(s, msk); s2 += __shfl_xor(s2, msk); }
        float mu = s * (1.f / CH), var = s2 * (1.f / CH) - mu * mu;
        float rr = rsqrtf(var + 1e-5f);
        #pragma unroll
        for (int j = 0; j < 8; ++j) {
            int col = j * 16 + l15;
            r1h[row * CH + col] = f2b(vals[j]);
            Al[rl0 + lg * 4 + r][col] = f2b((vals[j] - mu) * rr * g2[col] + b2[col]);
        }
    }
    __syncthreads();

    // hoisted A-fragments of LN2 output (constant across chunks)
    bf16x8 afb[4];
    #pragma unroll
    for (int ks = 0; ks < 4; ++ks)
        afb[ks] = *(const bf16x8*)&Al[rl0 + l15][ks * 32 + lg * 8];

    f32x4 a2[8] = {};
    for (int c = 0; c < 5; ++c) {
        // ---- Phase B: GLU chunk (64 u-cols + 64 g-cols) ----
        f32x4 au[4] = {}, ag[4] = {};
        #pragma unroll
        for (int j = 0; j < 4; ++j)
            #pragma unroll
            for (int ks = 0; ks < 4; ++ks) {
                bf16x8 bu = *(const bf16x8*)&wg[(long)(c * 64 + j * 16 + l15) * CH + ks * 32 + lg * 8];
                bf16x8 bg = *(const bf16x8*)&wg[(long)(GLUI + c * 64 + j * 16 + l15) * CH + ks * 32 + lg * 8];
                au[j] = __builtin_amdgcn_mfma_f32_16x16x32_bf16(afb[ks], bu, au[j], 0, 0, 0);
                ag[j] = __builtin_amdgcn_mfma_f32_16x16x32_bf16(afb[ks], bg, ag[j], 0, 0, 0);
            }
        #pragma unroll
        for (int j = 0; j < 4; ++j) {
            float bu_ = glu_b[c * 64 + j * 16 + l15];
            float bg_ = glu_b[GLUI + c * 64 + j * 16 + l15];
            #pragma unroll
            for (int r = 0; r < 4; ++r) {
                float uu = au[j][r] + bu_;
                float gg = ag[j][r] + bg_;
                float ge = 0.5f * gg * (1.f + erff(gg * 0.70710678118654752f));
                Ac[rl0 + lg * 4 + r][j * 16 + l15] = f2b(uu * ge);
            }
        }
        __syncthreads();
        // ---- Phase C: partial out-GEMM over this K-chunk of 64 ----
        #pragma unroll
        for (int ks2 = 0; ks2 < 2; ++ks2) {
            bf16x8 af2 = *(const bf16x8*)&Ac[rl0 + l15][ks2 * 32 + lg * 8];
            #pragma unroll
            for (int j = 0; j < 8; ++j) {
                bf16x8 bo = *(const bf16x8*)&wo[(long)(j * 16 + l15) * GLUI + c * 64 + ks2 * 32 + lg * 8];
                a2[j] = __builtin_amdgcn_mfma_f32_16x16x32_bf16(af2, bo, a2[j], 0, 0, 0);
            }
        }
        __syncthreads();
    }
    #pragma unroll
    for (int j = 0; j < 8; ++j) {
        int col = j * 16 + l15;
        float bc = out_b[col];
        #pragma unroll
        for (int r = 0; r < 4; ++r) {
            long row = m0 + rl0 + lg * 4 + r;
            mlph[row * CH + col] = f2b(a2[j][r] + bc);
        }
    }
}

// ---------------- chunk sums of mlp (bf16) for the CB mean ------------------
__global__ __launch_bounds__(256) void k_csum(const u16* __restrict__ mlph,
                                              const int* __restrict__ iw,
                                              float* __restrict__ csum) {
    __shared__ float acc[2][8][CH];
    int tid = threadIdx.x, c = tid & 127, half = tid >> 7;
    #pragma unroll
    for (int i = 0; i < 8; ++i) acc[half][i][c] = 0.f;
    int base = blockIdx.x * 256;
    for (int r = base + half; r < base + 256; r += 2) {
        int cid = iw[r / KA] >> 8;
        acc[half][cid][c] += b2f(mlph[(long)r * CH + c]);
    }
    __syncthreads();
    if (half == 0)
        #pragma unroll
        for (int i = 0; i < 8; ++i)
            atomicAdd(&csum[i * CH + c], acc[0][i][c] + acc[1][i][c]);
}

// ---------------- finalize + scatter (8 cols/thread) ------------------------
__global__ __launch_bounds__(256) void k_final(const u16* __restrict__ r1h,
                                               const u16* __restrict__ mlph,
                                               const float* __restrict__ csum,
                                               const float* __restrict__ ls2,
                                               const int* __restrict__ iw,
                                               const int* __restrict__ ecb,
                                               float* __restrict__ out) {
    long idx8 = (long)blockIdx.x * 256 + threadIdx.x;   // < 983040
    long row = idx8 >> 4;
    int seg = (int)(idx8 & 15) * 8;
    int m = (int)(row / KA), k = (int)(row % KA);
    int w = iw[m];
    int cb = ecb[0];
    int cid = w >> 8;
    bf16x8 rv = *(const bf16x8*)&r1h[row * CH + seg];
    bf16x8 mv = *(const bf16x8*)&mlph[row * CH + seg];
    float* dst = out + ((long)(w * PW + k)) * CH + seg;
    float4 o0, o1;
    float ot[8];
    #pragma unroll
    for (int t = 0; t < 8; ++t) {
        float xa = b2f((u16)mv[t]);
        if (cb) xa = 0.5f * xa + (0.5f / RPC) * csum[cid * CH + seg + t];
        ot[t] = b2f((u16)rv[t]) + xa * ls2[seg + t];
    }
    o0.x = ot[0]; o0.y = ot[1]; o0.z = ot[2]; o0.w = ot[3];
    o1.x = ot[4]; o1.y = ot[5]; o1.z = ot[6]; o1.w = ot[7];
    *(float4*)dst = o0;
    *(float4*)(dst + 4) = o1;
}

extern "C" void kernel_launch(void* const* d_in, const int* in_sizes, int n_in,
                              void* d_out, int out_size, void* d_ws, size_t ws_size,
                              hipStream_t stream) {
    const float* x      = (const float*)d_in[0];
    const float* n1g    = (const float*)d_in[1];
    const float* n1b    = (const float*)d_in[2];
    const float* n2g    = (const float*)d_in[3];
    const float* n2b    = (const float*)d_in[4];
    const float* qkv_w  = (const float*)d_in[5];
    const float* qkv_b  = (const float*)d_in[6];
    const float* proj_w = (const float*)d_in[7];
    const float* proj_b = (const float*)d_in[8];
    const float* ls1    = (const float*)d_in[9];
    const float* ls2    = (const float*)d_in[10];
    const float* glu_w  = (const float*)d_in[11];
    const float* glu_b  = (const float*)d_in[12];
    const float* out_w  = (const float*)d_in[13];
    const float* out_b  = (const float*)d_in[14];
    const int*   iw     = (const int*)d_in[15];
    const int*   ecb    = (const int*)d_in[21];
    float* out = (float*)d_out;

    char* w = (char*)d_ws;
    u16*   s1h  = (u16*)w;                          // 15,728,640
    u16*   qkvb = (u16*)(w + 15728640);             // 47,185,920
    u16*   obuf = (u16*)(w + 62914560);             // 15,728,640
    u16*   r1h  = (u16*)(w + 78643200);             // 15,728,640
    u16*   mlph = (u16*)(w + 94371840);             // 15,728,640
    u16*   wq   = (u16*)(w + 110100480);            // 384x128
    u16*   wp   = wq + 384 * 128;
    u16*   wg   = wp + 128 * 128;
    u16*   wo   = wg + 640 * 128;
    float* csum = (float*)(w + 110100480 + 2 * (384*128 + 128*128 + 640*128 + 128*320));

    k_cvt<<<(188416 + 255) / 256, 256, 0, stream>>>(qkv_w, proj_w, glu_w, out_w, wq, wp, wg, wo);
    hipMemsetAsync(csum, 0, 8 * CH * sizeof(float), stream);

    k_ln1 <<<N_WIN * PW / 8, 256, 0, stream>>>(x, n1g, n1b, out);
    k_ln2a<<<NTOK / 8, 256, 0, stream>>>(out, n2g, n2b, iw, s1h);
    k_qkv <<<dim3(NTOK / 64, 2), 256, 0, stream>>>(s1h, wq, qkv_b, qkvb);
    k_attn<<<MSEL, 256, 0, stream>>>(qkvb, obuf);
    k_mega<<<NTOK / 64, 256, 0, stream>>>(obuf, s1h, wp, proj_b, ls1, n2g, n2b,
                                          wg, glu_b, wo, out_b, r1h, mlph);
    k_csum<<<NTOK / 256, 256, 0, stream>>>(mlph, iw, csum);
    k_final<<<(NTOK * CH / 8) / 256, 256, 0, stream>>>(r1h, mlph, csum, ls2, iw, ecb, out);
    (void)in_sizes; (void)n_in; (void)out_size; (void)ws_size;
}

// Round 5
// 330.124 us; speedup vs baseline: 1.0560x; 1.0560x over previous
//
#include <hip/hip_runtime.h>
#include <math.h>

typedef unsigned short u16;
typedef unsigned int   u32;
typedef __attribute__((ext_vector_type(8))) short bf16x8;
typedef __attribute__((ext_vector_type(4))) float f32x4;

#define N_WIN 2048
#define PW    64
#define KA    40
#define MSEL  1536
#define CH    128
#define NH    4
#define GLUI  320
#define NTOK  (MSEL*KA)          // 61440
#define RPC   16384              // rows per chunk (CB mean)

__device__ __forceinline__ u16 f2b(float f) {
    u32 u = __float_as_uint(f);
    return (u16)((u + 0x7FFFu + ((u >> 16) & 1u)) >> 16);
}
__device__ __forceinline__ float b2f(u16 v) { return __uint_as_float(((u32)v) << 16); }

// ---------------- all weights fp32 -> bf16 transposed, one launch -----------
__global__ __launch_bounds__(256) void k_cvt(const float* __restrict__ qkv_w,
                                             const float* __restrict__ proj_w,
                                             const float* __restrict__ glu_w,
                                             const float* __restrict__ out_w,
                                             u16* __restrict__ wq, u16* __restrict__ wp,
                                             u16* __restrict__ wg, u16* __restrict__ wo) {
    int idx = blockIdx.x * 256 + threadIdx.x;
    if (idx < 49152) {
        int n = idx / 128, k = idx % 128;
        wq[idx] = f2b(qkv_w[k * 384 + n]);
    } else if (idx < 65536) {
        int i = idx - 49152, n = i / 128, k = i % 128;
        wp[i] = f2b(proj_w[k * 128 + n]);
    } else if (idx < 147456) {
        int i = idx - 65536, n = i / 128, k = i % 128;
        wg[i] = f2b(glu_w[k * 640 + n]);
    } else if (idx < 188416) {
        int i = idx - 147456, n = i / 320, k = i % 320;
        wo[i] = f2b(out_w[k * 128 + n]);
    }
}

// ---------------- LN1 over all 131072 rows -> d_out (float4, 2 rows/wave) ---
__global__ __launch_bounds__(256) void k_ln1(const float* __restrict__ x,
                                             const float* __restrict__ g,
                                             const float* __restrict__ b,
                                             float* __restrict__ out) {
    int wave = threadIdx.x >> 6, lane = threadIdx.x & 63;
    long row = (long)blockIdx.x * 8 + wave * 2 + (lane >> 5);
    int col = (lane & 31) * 4;
    float4 v = *(const float4*)(x + row * CH + col);
    float s  = v.x + v.y + v.z + v.w;
    float s2 = v.x * v.x + v.y * v.y + v.z * v.z + v.w * v.w;
    #pragma unroll
    for (int o = 16; o; o >>= 1) { s += __shfl_xor(s, o); s2 += __shfl_xor(s2, o); }
    float mu = s * (1.f / CH), var = s2 * (1.f / CH) - mu * mu;
    float r = rsqrtf(var + 1e-5f);
    float4 gg = *(const float4*)(g + col);
    float4 bb = *(const float4*)(b + col);
    float4 o4;
    o4.x = (v.x - mu) * r * gg.x + bb.x;
    o4.y = (v.y - mu) * r * gg.y + bb.y;
    o4.z = (v.z - mu) * r * gg.z + bb.z;
    o4.w = (v.w - mu) * r * gg.w + bb.w;
    *(float4*)(out + row * CH + col) = o4;
}

// ---------------- gather + LN2 -> s1h bf16 ----------------------------------
__global__ __launch_bounds__(256) void k_ln2a(const float* __restrict__ ln1,
                                              const float* __restrict__ g2,
                                              const float* __restrict__ b2,
                                              const int* __restrict__ iw,
                                              u16* __restrict__ s1h) {
    int wave = threadIdx.x >> 6, lane = threadIdx.x & 63;
    long row = (long)blockIdx.x * 8 + wave * 2 + (lane >> 5);   // < 61440
    int col = (lane & 31) * 4;
    int m = (int)(row / KA), r = (int)(row % KA);
    const float* src = ln1 + ((long)iw[m] * PW + r) * CH + col;
    float4 v = *(const float4*)src;
    float s  = v.x + v.y + v.z + v.w;
    float s2 = v.x * v.x + v.y * v.y + v.z * v.z + v.w * v.w;
    #pragma unroll
    for (int o = 16; o; o >>= 1) { s += __shfl_xor(s, o); s2 += __shfl_xor(s2, o); }
    float mu = s * (1.f / CH), var = s2 * (1.f / CH) - mu * mu;
    float rr = rsqrtf(var + 1e-5f);
    float4 gg = *(const float4*)(g2 + col);
    float4 bb = *(const float4*)(b2 + col);
    ushort4 o4;
    o4.x = f2b((v.x - mu) * rr * gg.x + bb.x);
    o4.y = f2b((v.y - mu) * rr * gg.y + bb.y);
    o4.z = f2b((v.z - mu) * rr * gg.z + bb.z);
    o4.w = f2b((v.w - mu) * rr * gg.w + bb.w);
    *(ushort4*)(s1h + row * CH + col) = o4;
}

// ---------------- per-window attention with fused QKV -----------------------
// Phase 0: stage s1 rows (sA, aliases vT). Phase 1: QKV = sA @ wq^T + b -> qk
// (per wave = head, 72 MFMA). Phase 2: vT from qk (overwrites sA). Phase 3:
// S=QK^T, softmax (P into dead q/k cols), O=PV, write obuf.
__global__ __launch_bounds__(256) void k_attn(const u16* __restrict__ s1h,
                                              const u16* __restrict__ wq,
                                              const float* __restrict__ qkv_b,
                                              u16* __restrict__ obuf) {
    __shared__ u16 qk[KA][392];        // 31.4 KB
    __shared__ u16 vT[NH][32][72];     // 18.4 KB ; first 10.9 KB aliased as sA
    u16 (*sA)[136] = (u16(*)[136])&vT[0][0][0];
    int m = blockIdx.x, tid = threadIdx.x;
    int h = tid >> 6, lane = tid & 63, l15 = lane & 15, lg = lane >> 4;

    // stage s1 rows of this window
    for (int i = tid; i < KA * 16; i += 256) {
        int row = i >> 4, seg = i & 15;
        *(bf16x8*)&sA[row][seg * 8] = *(const bf16x8*)&s1h[((long)m * KA + row) * CH + seg * 8];
    }
    __syncthreads();

    // QKV: cols h*96 .. h*96+95 for all 40 rows
    #pragma unroll
    for (int mi = 0; mi < 3; ++mi) {
        int rr = mi * 16 + l15; if (rr > KA - 1) rr = KA - 1;
        bf16x8 af[4];
        #pragma unroll
        for (int ks = 0; ks < 4; ++ks) af[ks] = *(const bf16x8*)&sA[rr][ks * 32 + lg * 8];
        f32x4 acc[6] = {};
        #pragma unroll
        for (int j = 0; j < 6; ++j)
            #pragma unroll
            for (int ks = 0; ks < 4; ++ks) {
                bf16x8 bfr = *(const bf16x8*)&wq[(long)(h * 96 + j * 16 + l15) * CH + ks * 32 + lg * 8];
                acc[j] = __builtin_amdgcn_mfma_f32_16x16x32_bf16(af[ks], bfr, acc[j], 0, 0, 0);
            }
        #pragma unroll
        for (int j = 0; j < 6; ++j) {
            float bc = qkv_b[h * 96 + j * 16 + l15];
            #pragma unroll
            for (int r = 0; r < 4; ++r) {
                int row = mi * 16 + lg * 4 + r;
                if (row < KA) qk[row][h * 96 + j * 16 + l15] = f2b(acc[j][r] + bc);
            }
        }
    }
    __syncthreads();

    // vT[h][d][key] (zero tail keys >= 40); overwrites sA (dead)
    for (int i = tid; i < NH * 32 * 64; i += 256) {
        int hh = i / (32 * 64), rem = i % (32 * 64), d = rem / 64, j = rem % 64;
        vT[hh][d][j] = (j < KA) ? qk[j][hh * 96 + 64 + d] : (u16)0;
    }
    __syncthreads();

    // S = Q @ K^T
    bf16x8 aq[3], bk[3];
    #pragma unroll
    for (int t = 0; t < 3; ++t) {
        int rr = t * 16 + l15; if (rr > KA - 1) rr = KA - 1;
        aq[t] = *(const bf16x8*)&qk[rr][h * 96 + lg * 8];
        bk[t] = *(const bf16x8*)&qk[rr][h * 96 + 32 + lg * 8];
    }
    f32x4 zero = {};
    f32x4 s[3][3];
    #pragma unroll
    for (int mi = 0; mi < 3; ++mi)
        #pragma unroll
        for (int ni = 0; ni < 3; ++ni)
            s[mi][ni] = __builtin_amdgcn_mfma_f32_16x16x32_bf16(aq[mi], bk[ni], zero, 0, 0, 0);

    const float scale = 0.17677669529663687f;
    float inv_[3][4];
    #pragma unroll
    for (int mi = 0; mi < 3; ++mi)
        #pragma unroll
        for (int r = 0; r < 4; ++r) {
            float v0 = s[mi][0][r] * scale;
            float v1 = s[mi][1][r] * scale;
            float v2 = (l15 >= 8) ? -1e30f : s[mi][2][r] * scale;   // mask keys >= 40
            float mx = fmaxf(fmaxf(v0, v1), v2);
            #pragma unroll
            for (int o = 1; o < 16; o <<= 1) mx = fmaxf(mx, __shfl_xor(mx, o));
            float e0 = __expf(v0 - mx), e1 = __expf(v1 - mx), e2 = __expf(v2 - mx);
            float sm = e0 + e1 + e2;
            #pragma unroll
            for (int o = 1; o < 16; o <<= 1) sm += __shfl_xor(sm, o);
            inv_[mi][r] = 1.f / sm;
            int row = mi * 16 + lg * 4 + r;
            if (row < KA) {
                qk[row][h * 96 + l15]      = f2b(e0);
                qk[row][h * 96 + 16 + l15] = f2b(e1);
                qk[row][h * 96 + 32 + l15] = f2b(e2);
            }
        }

    // O = P @ V  (stale P cols 48..63 multiply vT zeros)
    f32x4 o[3][2] = {};
    #pragma unroll
    for (int ks = 0; ks < 2; ++ks) {
        bf16x8 pa[3], vb[2];
        #pragma unroll
        for (int mi = 0; mi < 3; ++mi) {
            int rp = mi * 16 + l15; if (rp > KA - 1) rp = KA - 1;
            pa[mi] = *(const bf16x8*)&qk[rp][h * 96 + ks * 32 + lg * 8];
        }
        #pragma unroll
        for (int nf = 0; nf < 2; ++nf) vb[nf] = *(const bf16x8*)&vT[h][nf * 16 + l15][ks * 32 + lg * 8];
        #pragma unroll
        for (int mi = 0; mi < 3; ++mi)
            #pragma unroll
            for (int nf = 0; nf < 2; ++nf)
                o[mi][nf] = __builtin_amdgcn_mfma_f32_16x16x32_bf16(pa[mi], vb[nf], o[mi][nf], 0, 0, 0);
    }
    #pragma unroll
    for (int mi = 0; mi < 3; ++mi)
        #pragma unroll
        for (int nf = 0; nf < 2; ++nf)
            #pragma unroll
            for (int r = 0; r < 4; ++r) {
                int row4 = mi * 16 + lg * 4 + r;
                if (row4 < KA)
                    obuf[((long)m * KA + row4) * CH + h * 32 + nf * 16 + l15] =
                        f2b(o[mi][nf][r] * inv_[mi][r]);
            }
}

// ---------------- proj GEMM (no LDS) + residual + fused LN2 -----------------
__global__ __launch_bounds__(256) void k_proj(const u16* __restrict__ obuf,
                                              const u16* __restrict__ wp,
                                              const float* __restrict__ proj_b,
                                              const u16* __restrict__ s1h,
                                              const float* __restrict__ ls1,
                                              const float* __restrict__ g2,
                                              const float* __restrict__ b2,
                                              u16* __restrict__ r1h,
                                              u16* __restrict__ hbuf) {
    int tid = threadIdx.x, wid = tid >> 6, lane = tid & 63;
    int l15 = lane & 15, lg = lane >> 4;
    long m0 = (long)blockIdx.x * 64 + wid * 16;
    bf16x8 af[4];
    #pragma unroll
    for (int ks = 0; ks < 4; ++ks)
        af[ks] = *(const bf16x8*)&obuf[(m0 + l15) * CH + ks * 32 + lg * 8];
    f32x4 ap[8] = {};
    #pragma unroll
    for (int j = 0; j < 8; ++j)
        #pragma unroll
        for (int ks = 0; ks < 4; ++ks) {
            bf16x8 bfr = *(const bf16x8*)&wp[(long)(j * 16 + l15) * CH + ks * 32 + lg * 8];
            ap[j] = __builtin_amdgcn_mfma_f32_16x16x32_bf16(af[ks], bfr, ap[j], 0, 0, 0);
        }
    #pragma unroll
    for (int r = 0; r < 4; ++r) {
        long row = m0 + lg * 4 + r;
        float vals[8]; float s = 0.f, s2 = 0.f;
        #pragma unroll
        for (int j = 0; j < 8; ++j) {
            int col = j * 16 + l15;
            float v = ap[j][r] + proj_b[col];
            v = b2f(s1h[row * CH + col]) + v * ls1[col];
            vals[j] = v; s += v; s2 += v * v;
        }
        #pragma unroll
        for (int msk = 1; msk < 16; msk <<= 1) { s += __shfl_xor(s, msk); s2 += __shfl_xor(s2, msk); }
        float mu = s * (1.f / CH), var = s2 * (1.f / CH) - mu * mu;
        float rr = rsqrtf(var + 1e-5f);
        #pragma unroll
        for (int j = 0; j < 8; ++j) {
            int col = j * 16 + l15;
            r1h[row * CH + col]  = f2b(vals[j]);
            hbuf[row * CH + col] = f2b((vals[j] - mu) * rr * g2[col] + b2[col]);
        }
    }
}

// ---------------- GLU GEMM (no LDS): grid (960, 4), 80 cols/block -----------
__global__ __launch_bounds__(256) void k_glu(const u16* __restrict__ hbuf,
                                             const u16* __restrict__ wg,
                                             const float* __restrict__ glu_b,
                                             u16* __restrict__ act) {
    int tid = threadIdx.x, wid = tid >> 6, lane = tid & 63;
    int l15 = lane & 15, lg = lane >> 4;
    long m0 = (long)blockIdx.x * 64 + wid * 16;
    int c0 = blockIdx.y * 80;
    bf16x8 af[4];
    #pragma unroll
    for (int ks = 0; ks < 4; ++ks)
        af[ks] = *(const bf16x8*)&hbuf[(m0 + l15) * CH + ks * 32 + lg * 8];
    f32x4 au[5] = {}, ag[5] = {};
    #pragma unroll
    for (int j = 0; j < 5; ++j)
        #pragma unroll
        for (int ks = 0; ks < 4; ++ks) {
            bf16x8 bu = *(const bf16x8*)&wg[(long)(c0 + j * 16 + l15) * CH + ks * 32 + lg * 8];
            bf16x8 bg = *(const bf16x8*)&wg[(long)(GLUI + c0 + j * 16 + l15) * CH + ks * 32 + lg * 8];
            au[j] = __builtin_amdgcn_mfma_f32_16x16x32_bf16(af[ks], bu, au[j], 0, 0, 0);
            ag[j] = __builtin_amdgcn_mfma_f32_16x16x32_bf16(af[ks], bg, ag[j], 0, 0, 0);
        }
    #pragma unroll
    for (int j = 0; j < 5; ++j) {
        int col = c0 + j * 16 + l15;
        float bu_ = glu_b[col], bg_ = glu_b[col + GLUI];
        #pragma unroll
        for (int r = 0; r < 4; ++r) {
            long row = m0 + lg * 4 + r;
            float uu = au[j][r] + bu_;
            float gg = ag[j][r] + bg_;
            float ge = 0.5f * gg * (1.f + erff(gg * 0.70710678118654752f));
            act[row * GLUI + col] = f2b(uu * ge);
        }
    }
}

// ---------------- OUT GEMM (no LDS): K=320 ----------------------------------
__global__ __launch_bounds__(256) void k_out(const u16* __restrict__ act,
                                             const u16* __restrict__ wo,
                                             const float* __restrict__ out_b,
                                             u16* __restrict__ mlph) {
    int tid = threadIdx.x, wid = tid >> 6, lane = tid & 63;
    int l15 = lane & 15, lg = lane >> 4;
    long m0 = (long)blockIdx.x * 64 + wid * 16;
    bf16x8 af[10];
    #pragma unroll
    for (int ks = 0; ks < 10; ++ks)
        af[ks] = *(const bf16x8*)&act[(m0 + l15) * GLUI + ks * 32 + lg * 8];
    f32x4 a2[8] = {};
    #pragma unroll
    for (int j = 0; j < 8; ++j)
        #pragma unroll
        for (int ks = 0; ks < 10; ++ks) {
            bf16x8 bo = *(const bf16x8*)&wo[(long)(j * 16 + l15) * GLUI + ks * 32 + lg * 8];
            a2[j] = __builtin_amdgcn_mfma_f32_16x16x32_bf16(af[ks], bo, a2[j], 0, 0, 0);
        }
    #pragma unroll
    for (int j = 0; j < 8; ++j) {
        int col = j * 16 + l15;
        float bc = out_b[col];
        #pragma unroll
        for (int r = 0; r < 4; ++r) {
            long row = m0 + lg * 4 + r;
            mlph[row * CH + col] = f2b(a2[j][r] + bc);
        }
    }
}

// ---------------- chunk sums of mlp (bf16) for the CB mean ------------------
__global__ __launch_bounds__(256) void k_csum(const u16* __restrict__ mlph,
                                              const int* __restrict__ iw,
                                              float* __restrict__ csum) {
    __shared__ float acc[2][8][CH];
    int tid = threadIdx.x, c = tid & 127, half = tid >> 7;
    #pragma unroll
    for (int i = 0; i < 8; ++i) acc[half][i][c] = 0.f;
    int base = blockIdx.x * 256;
    for (int r = base + half; r < base + 256; r += 2) {
        int cid = iw[r / KA] >> 8;
        acc[half][cid][c] += b2f(mlph[(long)r * CH + c]);
    }
    __syncthreads();
    if (half == 0)
        #pragma unroll
        for (int i = 0; i < 8; ++i)
            atomicAdd(&csum[i * CH + c], acc[0][i][c] + acc[1][i][c]);
}

// ---------------- finalize + scatter (8 cols/thread) ------------------------
__global__ __launch_bounds__(256) void k_final(const u16* __restrict__ r1h,
                                               const u16* __restrict__ mlph,
                                               const float* __restrict__ csum,
                                               const float* __restrict__ ls2,
                                               const int* __restrict__ iw,
                                               const int* __restrict__ ecb,
                                               float* __restrict__ out) {
    long idx8 = (long)blockIdx.x * 256 + threadIdx.x;   // < 983040
    long row = idx8 >> 4;
    int seg = (int)(idx8 & 15) * 8;
    int m = (int)(row / KA), k = (int)(row % KA);
    int w = iw[m];
    int cb = ecb[0];
    int cid = w >> 8;
    bf16x8 rv = *(const bf16x8*)&r1h[row * CH + seg];
    bf16x8 mv = *(const bf16x8*)&mlph[row * CH + seg];
    float* dst = out + ((long)(w * PW + k)) * CH + seg;
    float4 o0, o1;
    float ot[8];
    #pragma unroll
    for (int t = 0; t < 8; ++t) {
        float xa = b2f((u16)mv[t]);
        if (cb) xa = 0.5f * xa + (0.5f / RPC) * csum[cid * CH + seg + t];
        ot[t] = b2f((u16)rv[t]) + xa * ls2[seg + t];
    }
    o0.x = ot[0]; o0.y = ot[1]; o0.z = ot[2]; o0.w = ot[3];
    o1.x = ot[4]; o1.y = ot[5]; o1.z = ot[6]; o1.w = ot[7];
    *(float4*)dst = o0;
    *(float4*)(dst + 4) = o1;
}

extern "C" void kernel_launch(void* const* d_in, const int* in_sizes, int n_in,
                              void* d_out, int out_size, void* d_ws, size_t ws_size,
                              hipStream_t stream) {
    const float* x      = (const float*)d_in[0];
    const float* n1g    = (const float*)d_in[1];
    const float* n1b    = (const float*)d_in[2];
    const float* n2g    = (const float*)d_in[3];
    const float* n2b    = (const float*)d_in[4];
    const float* qkv_w  = (const float*)d_in[5];
    const float* qkv_b  = (const float*)d_in[6];
    const float* proj_w = (const float*)d_in[7];
    const float* proj_b = (const float*)d_in[8];
    const float* ls1    = (const float*)d_in[9];
    const float* ls2    = (const float*)d_in[10];
    const float* glu_w  = (const float*)d_in[11];
    const float* glu_b  = (const float*)d_in[12];
    const float* out_w  = (const float*)d_in[13];
    const float* out_b  = (const float*)d_in[14];
    const int*   iw     = (const int*)d_in[15];
    const int*   ecb    = (const int*)d_in[21];
    float* out = (float*)d_out;

    char* w = (char*)d_ws;
    u16*   s1h  = (u16*)w;                          // 15,728,640
    u16*   obuf = (u16*)(w + 15728640);             // 15,728,640
    u16*   r1h  = (u16*)(w + 31457280);             // 15,728,640
    u16*   hbuf = (u16*)(w + 47185920);             // 15,728,640
    u16*   act  = (u16*)(w + 62914560);             // 39,321,600
    u16*   mlph = (u16*)(w + 102236160);            // 15,728,640
    u16*   wq   = (u16*)(w + 117964800);            // 49152 u16
    u16*   wp   = wq + 384 * 128;                   // 16384 u16
    u16*   wg   = wp + 128 * 128;                   // 81920 u16
    u16*   wo   = wg + 640 * 128;                   // 40960 u16
    float* csum = (float*)(w + 117964800 + 376832);

    k_cvt<<<(188416 + 255) / 256, 256, 0, stream>>>(qkv_w, proj_w, glu_w, out_w, wq, wp, wg, wo);
    hipMemsetAsync(csum, 0, 8 * CH * sizeof(float), stream);

    k_ln1 <<<N_WIN * PW / 8, 256, 0, stream>>>(x, n1g, n1b, out);
    k_ln2a<<<NTOK / 8, 256, 0, stream>>>(out, n2g, n2b, iw, s1h);
    k_attn<<<MSEL, 256, 0, stream>>>(s1h, wq, qkv_b, obuf);
    k_proj<<<NTOK / 64, 256, 0, stream>>>(obuf, wp, proj_b, s1h, ls1, n2g, n2b, r1h, hbuf);
    k_glu <<<dim3(NTOK / 64, 4), 256, 0, stream>>>(hbuf, wg, glu_b, act);
    k_out <<<NTOK / 64, 256, 0, stream>>>(act, wo, out_b, mlph);
    k_csum<<<NTOK / 256, 256, 0, stream>>>(mlph, iw, csum);
    k_final<<<(NTOK * CH / 8) / 256, 256, 0, stream>>>(r1h, mlph, csum, ls2, iw, ecb, out);
    (void)in_sizes; (void)n_in; (void)out_size; (void)ws_size;
}

// Round 6
// 244.696 us; speedup vs baseline: 1.4247x; 1.3491x over previous
//
#include <hip/hip_runtime.h>
#include <math.h>

typedef unsigned short u16;
typedef unsigned int   u32;
typedef __attribute__((ext_vector_type(8))) short bf16x8;
typedef __attribute__((ext_vector_type(4))) float f32x4;

#define N_WIN 2048
#define PW    64
#define KA    40
#define MSEL  1536
#define CH    128
#define NH    4
#define GLUI  320
#define NTOK  (MSEL*KA)          // 61440
#define RPC   16384              // rows per chunk (CB mean)

__device__ __forceinline__ u16 f2b(float f) {
    u32 u = __float_as_uint(f);
    return (u16)((u + 0x7FFFu + ((u >> 16) & 1u)) >> 16);
}
__device__ __forceinline__ float b2f(u16 v) { return __uint_as_float(((u32)v) << 16); }

// ---------------- all weights fp32 -> bf16 transposed, one launch -----------
__global__ __launch_bounds__(256) void k_cvt(const float* __restrict__ qkv_w,
                                             const float* __restrict__ proj_w,
                                             const float* __restrict__ glu_w,
                                             const float* __restrict__ out_w,
                                             u16* __restrict__ wq, u16* __restrict__ wp,
                                             u16* __restrict__ wg, u16* __restrict__ wo) {
    int idx = blockIdx.x * 256 + threadIdx.x;
    if (idx < 49152) {
        int n = idx / 128, k = idx % 128;
        wq[idx] = f2b(qkv_w[k * 384 + n]);
    } else if (idx < 65536) {
        int i = idx - 49152, n = i / 128, k = i % 128;
        wp[i] = f2b(proj_w[k * 128 + n]);
    } else if (idx < 147456) {
        int i = idx - 65536, n = i / 128, k = i % 128;
        wg[i] = f2b(glu_w[k * 640 + n]);
    } else if (idx < 188416) {
        int i = idx - 147456, n = i / 320, k = i % 320;
        wo[i] = f2b(out_w[k * 128 + n]);
    }
}

// ---------------- LN1 over all 131072 rows -> d_out -------------------------
__global__ __launch_bounds__(256) void k_ln1(const float* __restrict__ x,
                                             const float* __restrict__ g,
                                             const float* __restrict__ b,
                                             float* __restrict__ out) {
    int wave = threadIdx.x >> 6, lane = threadIdx.x & 63;
    long row = (long)blockIdx.x * 8 + wave * 2 + (lane >> 5);
    int col = (lane & 31) * 4;
    float4 v = *(const float4*)(x + row * CH + col);
    float s  = v.x + v.y + v.z + v.w;
    float s2 = v.x * v.x + v.y * v.y + v.z * v.z + v.w * v.w;
    #pragma unroll
    for (int o = 16; o; o >>= 1) { s += __shfl_xor(s, o); s2 += __shfl_xor(s2, o); }
    float mu = s * (1.f / CH), var = s2 * (1.f / CH) - mu * mu;
    float r = rsqrtf(var + 1e-5f);
    float4 gg = *(const float4*)(g + col);
    float4 bb = *(const float4*)(b + col);
    float4 o4;
    o4.x = (v.x - mu) * r * gg.x + bb.x;
    o4.y = (v.y - mu) * r * gg.y + bb.y;
    o4.z = (v.z - mu) * r * gg.z + bb.z;
    o4.w = (v.w - mu) * r * gg.w + bb.w;
    *(float4*)(out + row * CH + col) = o4;
}

// ---------------- gather + LN2 -> s1h bf16 ----------------------------------
__global__ __launch_bounds__(256) void k_ln2a(const float* __restrict__ ln1,
                                              const float* __restrict__ g2,
                                              const float* __restrict__ b2,
                                              const int* __restrict__ iw,
                                              u16* __restrict__ s1h) {
    int wave = threadIdx.x >> 6, lane = threadIdx.x & 63;
    long row = (long)blockIdx.x * 8 + wave * 2 + (lane >> 5);   // < 61440
    int col = (lane & 31) * 4;
    int m = (int)(row / KA), r = (int)(row % KA);
    const float* src = ln1 + ((long)iw[m] * PW + r) * CH + col;
    float4 v = *(const float4*)src;
    float s  = v.x + v.y + v.z + v.w;
    float s2 = v.x * v.x + v.y * v.y + v.z * v.z + v.w * v.w;
    #pragma unroll
    for (int o = 16; o; o >>= 1) { s += __shfl_xor(s, o); s2 += __shfl_xor(s2, o); }
    float mu = s * (1.f / CH), var = s2 * (1.f / CH) - mu * mu;
    float rr = rsqrtf(var + 1e-5f);
    float4 gg = *(const float4*)(g2 + col);
    float4 bb = *(const float4*)(b2 + col);
    ushort4 o4;
    o4.x = f2b((v.x - mu) * rr * gg.x + bb.x);
    o4.y = f2b((v.y - mu) * rr * gg.y + bb.y);
    o4.z = f2b((v.z - mu) * rr * gg.z + bb.z);
    o4.w = f2b((v.w - mu) * rr * gg.w + bb.w);
    *(ushort4*)(s1h + row * CH + col) = o4;
}

// ---------------- QKV GEMM: reg-B (24 frags/wave) + LDS-A -------------------
__global__ __launch_bounds__(256, 3) void k_qkv(const u16* __restrict__ A,
                                                const u16* __restrict__ wq,
                                                const float* __restrict__ qkv_b,
                                                u16* __restrict__ qkvb) {
    __shared__ u16 Al[64][136];
    int tid = threadIdx.x, wid = tid >> 6, lane = tid & 63;
    int l15 = lane & 15, lg = lane >> 4;
    long m0 = (long)blockIdx.x * 64;
    bf16x8 bf[6][4];
    #pragma unroll
    for (int j = 0; j < 6; ++j)
        #pragma unroll
        for (int ks = 0; ks < 4; ++ks)
            bf[j][ks] = *(const bf16x8*)&wq[(long)(wid * 96 + j * 16 + l15) * CH + ks * 32 + lg * 8];
    #pragma unroll
    for (int ch = 0; ch < 4; ++ch) {
        int id = tid + ch * 256; int row = id >> 4, c8 = id & 15;
        *(bf16x8*)&Al[row][c8 * 8] = *(const bf16x8*)&A[(m0 + row) * CH + c8 * 8];
    }
    __syncthreads();
    #pragma unroll
    for (int st = 0; st < 4; ++st) {
        bf16x8 af[4];
        #pragma unroll
        for (int ks = 0; ks < 4; ++ks) af[ks] = *(const bf16x8*)&Al[st * 16 + l15][ks * 32 + lg * 8];
        f32x4 acc[6] = {};
        #pragma unroll
        for (int j = 0; j < 6; ++j)
            #pragma unroll
            for (int ks = 0; ks < 4; ++ks)
                acc[j] = __builtin_amdgcn_mfma_f32_16x16x32_bf16(af[ks], bf[j][ks], acc[j], 0, 0, 0);
        #pragma unroll
        for (int j = 0; j < 6; ++j) {
            int col = wid * 96 + j * 16 + l15;
            float bc = qkv_b[col];
            #pragma unroll
            for (int r = 0; r < 4; ++r)
                qkvb[(m0 + st * 16 + lg * 4 + r) * 384 + col] = f2b(acc[j][r] + bc);
        }
    }
}

// ---------------- per-window MFMA attention (R3-proven form) -----------------
__global__ __launch_bounds__(256) void k_attn(const u16* __restrict__ qkvb,
                                              u16* __restrict__ obuf) {
    __shared__ u16 qk[KA][392];
    __shared__ u16 vT[NH][32][72];
    int m = blockIdx.x, tid = threadIdx.x;
    int h = tid >> 6, lane = tid & 63, l15 = lane & 15, lg = lane >> 4;

    for (int i = tid; i < KA * 48; i += 256) {
        int j = i / 48, seg = i % 48;
        *(bf16x8*)&qk[j][seg * 8] = *(const bf16x8*)&qkvb[((long)m * KA + j) * 384 + seg * 8];
    }
    __syncthreads();
    for (int i = tid; i < NH * 32 * 64; i += 256) {
        int hh = i / (32 * 64), rem = i % (32 * 64), d = rem / 64, j = rem % 64;
        vT[hh][d][j] = (j < KA) ? qk[j][hh * 96 + 64 + d] : (u16)0;
    }
    __syncthreads();

    bf16x8 aq[3], bk[3];
    #pragma unroll
    for (int t = 0; t < 3; ++t) {
        int rr = t * 16 + l15; if (rr > KA - 1) rr = KA - 1;
        aq[t] = *(const bf16x8*)&qk[rr][h * 96 + lg * 8];
        bk[t] = *(const bf16x8*)&qk[rr][h * 96 + 32 + lg * 8];
    }
    f32x4 zero = {};
    f32x4 s[3][3];
    #pragma unroll
    for (int mi = 0; mi < 3; ++mi)
        #pragma unroll
        for (int ni = 0; ni < 3; ++ni)
            s[mi][ni] = __builtin_amdgcn_mfma_f32_16x16x32_bf16(aq[mi], bk[ni], zero, 0, 0, 0);

    const float scale = 0.17677669529663687f;
    float inv_[3][4];
    #pragma unroll
    for (int mi = 0; mi < 3; ++mi)
        #pragma unroll
        for (int r = 0; r < 4; ++r) {
            float v0 = s[mi][0][r] * scale;
            float v1 = s[mi][1][r] * scale;
            float v2 = (l15 >= 8) ? -1e30f : s[mi][2][r] * scale;   // mask keys >= 40
            float mx = fmaxf(fmaxf(v0, v1), v2);
            #pragma unroll
            for (int o = 1; o < 16; o <<= 1) mx = fmaxf(mx, __shfl_xor(mx, o));
            float e0 = __expf(v0 - mx), e1 = __expf(v1 - mx), e2 = __expf(v2 - mx);
            float sm = e0 + e1 + e2;
            #pragma unroll
            for (int o = 1; o < 16; o <<= 1) sm += __shfl_xor(sm, o);
            inv_[mi][r] = 1.f / sm;
            int row = mi * 16 + lg * 4 + r;
            if (row < KA) {
                qk[row][h * 96 + l15]      = f2b(e0);
                qk[row][h * 96 + 16 + l15] = f2b(e1);
                qk[row][h * 96 + 32 + l15] = f2b(e2);
            }
        }

    f32x4 o[3][2] = {};
    #pragma unroll
    for (int ks = 0; ks < 2; ++ks) {
        bf16x8 pa[3], vb[2];
        #pragma unroll
        for (int mi = 0; mi < 3; ++mi) {
            int rp = mi * 16 + l15; if (rp > KA - 1) rp = KA - 1;
            pa[mi] = *(const bf16x8*)&qk[rp][h * 96 + ks * 32 + lg * 8];
        }
        #pragma unroll
        for (int nf = 0; nf < 2; ++nf) vb[nf] = *(const bf16x8*)&vT[h][nf * 16 + l15][ks * 32 + lg * 8];
        #pragma unroll
        for (int mi = 0; mi < 3; ++mi)
            #pragma unroll
            for (int nf = 0; nf < 2; ++nf)
                o[mi][nf] = __builtin_amdgcn_mfma_f32_16x16x32_bf16(pa[mi], vb[nf], o[mi][nf], 0, 0, 0);
    }
    #pragma unroll
    for (int mi = 0; mi < 3; ++mi)
        #pragma unroll
        for (int nf = 0; nf < 2; ++nf)
            #pragma unroll
            for (int r = 0; r < 4; ++r) {
                int row4 = mi * 16 + lg * 4 + r;
                if (row4 < KA)
                    obuf[((long)m * KA + row4) * CH + h * 32 + nf * 16 + l15] =
                        f2b(o[mi][nf][r] * inv_[mi][r]);
            }
}

// ---------------- proj: reg-B + LDS-A + residual + LN2 (cross-wave) ---------
__global__ __launch_bounds__(256, 3) void k_proj(const u16* __restrict__ obuf,
                                                 const u16* __restrict__ wp,
                                                 const float* __restrict__ proj_b,
                                                 const u16* __restrict__ s1h,
                                                 const float* __restrict__ ls1,
                                                 const float* __restrict__ g2,
                                                 const float* __restrict__ b2,
                                                 u16* __restrict__ r1h,
                                                 u16* __restrict__ hbuf) {
    __shared__ u16 Al[64][136];
    __shared__ float ps[4][64], ps2[4][64];
    int tid = threadIdx.x, wid = tid >> 6, lane = tid & 63;
    int l15 = lane & 15, lg = lane >> 4;
    long m0 = (long)blockIdx.x * 64;
    bf16x8 bf[2][4];
    #pragma unroll
    for (int j = 0; j < 2; ++j)
        #pragma unroll
        for (int ks = 0; ks < 4; ++ks)
            bf[j][ks] = *(const bf16x8*)&wp[(long)(wid * 32 + j * 16 + l15) * CH + ks * 32 + lg * 8];
    #pragma unroll
    for (int ch = 0; ch < 4; ++ch) {
        int id = tid + ch * 256; int row = id >> 4, c8 = id & 15;
        *(bf16x8*)&Al[row][c8 * 8] = *(const bf16x8*)&obuf[(m0 + row) * CH + c8 * 8];
    }
    __syncthreads();
    float vals[4][2][4];
    #pragma unroll
    for (int st = 0; st < 4; ++st) {
        bf16x8 af[4];
        #pragma unroll
        for (int ks = 0; ks < 4; ++ks) af[ks] = *(const bf16x8*)&Al[st * 16 + l15][ks * 32 + lg * 8];
        f32x4 acc[2] = {};
        #pragma unroll
        for (int j = 0; j < 2; ++j)
            #pragma unroll
            for (int ks = 0; ks < 4; ++ks)
                acc[j] = __builtin_amdgcn_mfma_f32_16x16x32_bf16(af[ks], bf[j][ks], acc[j], 0, 0, 0);
        #pragma unroll
        for (int r = 0; r < 4; ++r) {
            long row = m0 + st * 16 + lg * 4 + r;
            float s = 0.f, s2 = 0.f;
            #pragma unroll
            for (int j = 0; j < 2; ++j) {
                int col = wid * 32 + j * 16 + l15;
                float v = acc[j][r] + proj_b[col];
                v = b2f(s1h[row * CH + col]) + v * ls1[col];
                vals[st][j][r] = v; s += v; s2 += v * v;
            }
            #pragma unroll
            for (int msk = 1; msk < 16; msk <<= 1) { s += __shfl_xor(s, msk); s2 += __shfl_xor(s2, msk); }
            if (l15 == 0) {
                ps[wid][st * 16 + lg * 4 + r]  = s;
                ps2[wid][st * 16 + lg * 4 + r] = s2;
            }
        }
    }
    __syncthreads();
    #pragma unroll
    for (int st = 0; st < 4; ++st)
        #pragma unroll
        for (int r = 0; r < 4; ++r) {
            int rl = st * 16 + lg * 4 + r;
            long row = m0 + rl;
            float s  = ps[0][rl] + ps[1][rl] + ps[2][rl] + ps[3][rl];
            float s2 = ps2[0][rl] + ps2[1][rl] + ps2[2][rl] + ps2[3][rl];
            float mu = s * (1.f / CH), var = s2 * (1.f / CH) - mu * mu;
            float rr = rsqrtf(var + 1e-5f);
            #pragma unroll
            for (int j = 0; j < 2; ++j) {
                int col = wid * 32 + j * 16 + l15;
                float v = vals[st][j][r];
                r1h[row * CH + col]  = f2b(v);
                hbuf[row * CH + col] = f2b((v - mu) * rr * g2[col] + b2[col]);
            }
        }
}

// ---------------- GLU: reg-B (40 frags/wave) + LDS-A + gelu -----------------
__global__ __launch_bounds__(256, 2) void k_glu(const u16* __restrict__ hbuf,
                                                const u16* __restrict__ wg,
                                                const float* __restrict__ glu_b,
                                                u16* __restrict__ act) {
    __shared__ u16 Al[64][136];
    int tid = threadIdx.x, wid = tid >> 6, lane = tid & 63;
    int l15 = lane & 15, lg = lane >> 4;
    long m0 = (long)blockIdx.x * 64;
    bf16x8 bu[5][4], bg[5][4];
    #pragma unroll
    for (int j = 0; j < 5; ++j)
        #pragma unroll
        for (int ks = 0; ks < 4; ++ks) {
            bu[j][ks] = *(const bf16x8*)&wg[(long)(wid * 80 + j * 16 + l15) * CH + ks * 32 + lg * 8];
            bg[j][ks] = *(const bf16x8*)&wg[(long)(GLUI + wid * 80 + j * 16 + l15) * CH + ks * 32 + lg * 8];
        }
    #pragma unroll
    for (int ch = 0; ch < 4; ++ch) {
        int id = tid + ch * 256; int row = id >> 4, c8 = id & 15;
        *(bf16x8*)&Al[row][c8 * 8] = *(const bf16x8*)&hbuf[(m0 + row) * CH + c8 * 8];
    }
    __syncthreads();
    #pragma unroll
    for (int st = 0; st < 4; ++st) {
        bf16x8 af[4];
        #pragma unroll
        for (int ks = 0; ks < 4; ++ks) af[ks] = *(const bf16x8*)&Al[st * 16 + l15][ks * 32 + lg * 8];
        f32x4 au[5] = {}, ag[5] = {};
        #pragma unroll
        for (int j = 0; j < 5; ++j)
            #pragma unroll
            for (int ks = 0; ks < 4; ++ks) {
                au[j] = __builtin_amdgcn_mfma_f32_16x16x32_bf16(af[ks], bu[j][ks], au[j], 0, 0, 0);
                ag[j] = __builtin_amdgcn_mfma_f32_16x16x32_bf16(af[ks], bg[j][ks], ag[j], 0, 0, 0);
            }
        #pragma unroll
        for (int j = 0; j < 5; ++j) {
            int col = wid * 80 + j * 16 + l15;
            float bu_ = glu_b[col], bg_ = glu_b[col + GLUI];
            #pragma unroll
            for (int r = 0; r < 4; ++r) {
                long row = m0 + st * 16 + lg * 4 + r;
                float uu = au[j][r] + bu_;
                float gg = ag[j][r] + bg_;
                float ge = 0.5f * gg * (1.f + erff(gg * 0.70710678118654752f));
                act[row * GLUI + col] = f2b(uu * ge);
            }
        }
    }
}

// ---------------- OUT: reg-B (40 frags/wave, 2x2 wave split) + LDS-A --------
__global__ __launch_bounds__(256, 2) void k_out(const u16* __restrict__ act,
                                                const u16* __restrict__ wo,
                                                const float* __restrict__ out_b,
                                                u16* __restrict__ mlph) {
    __shared__ u16 Al[64][328];
    int tid = threadIdx.x, wid = tid >> 6, lane = tid & 63;
    int l15 = lane & 15, lg = lane >> 4;
    int cg = wid & 1, rh = wid >> 1;
    long m0 = (long)blockIdx.x * 64;
    bf16x8 bo[4][10];
    #pragma unroll
    for (int j = 0; j < 4; ++j)
        #pragma unroll
        for (int ks = 0; ks < 10; ++ks)
            bo[j][ks] = *(const bf16x8*)&wo[(long)(cg * 64 + j * 16 + l15) * GLUI + ks * 32 + lg * 8];
    #pragma unroll
    for (int ch = 0; ch < 10; ++ch) {
        int id = tid + ch * 256; int row = id / 40, c8 = id % 40;
        *(bf16x8*)&Al[row][c8 * 8] = *(const bf16x8*)&act[(m0 + row) * GLUI + c8 * 8];
    }
    __syncthreads();
    #pragma unroll
    for (int st2 = 0; st2 < 2; ++st2) {
        int st = rh * 2 + st2;
        f32x4 acc[4] = {};
        #pragma unroll
        for (int ks = 0; ks < 10; ++ks) {
            bf16x8 af = *(const bf16x8*)&Al[st * 16 + l15][ks * 32 + lg * 8];
            #pragma unroll
            for (int j = 0; j < 4; ++j)
                acc[j] = __builtin_amdgcn_mfma_f32_16x16x32_bf16(af, bo[j][ks], acc[j], 0, 0, 0);
        }
        #pragma unroll
        for (int j = 0; j < 4; ++j) {
            int col = cg * 64 + j * 16 + l15;
            float bc = out_b[col];
            #pragma unroll
            for (int r = 0; r < 4; ++r)
                mlph[(m0 + st * 16 + lg * 4 + r) * CH + col] = f2b(acc[j][r] + bc);
        }
    }
}

// ---------------- chunk sums of mlp (bf16) for the CB mean ------------------
__global__ __launch_bounds__(256) void k_csum(const u16* __restrict__ mlph,
                                              const int* __restrict__ iw,
                                              float* __restrict__ csum) {
    __shared__ float acc[2][8][CH];
    int tid = threadIdx.x, c = tid & 127, half = tid >> 7;
    #pragma unroll
    for (int i = 0; i < 8; ++i) acc[half][i][c] = 0.f;
    int base = blockIdx.x * 256;
    for (int r = base + half; r < base + 256; r += 2) {
        int cid = iw[r / KA] >> 8;
        acc[half][cid][c] += b2f(mlph[(long)r * CH + c]);
    }
    __syncthreads();
    if (half == 0)
        #pragma unroll
        for (int i = 0; i < 8; ++i)
            atomicAdd(&csum[i * CH + c], acc[0][i][c] + acc[1][i][c]);
}

// ---------------- finalize + scatter (8 cols/thread) ------------------------
__global__ __launch_bounds__(256) void k_final(const u16* __restrict__ r1h,
                                               const u16* __restrict__ mlph,
                                               const float* __restrict__ csum,
                                               const float* __restrict__ ls2,
                                               const int* __restrict__ iw,
                                               const int* __restrict__ ecb,
                                               float* __restrict__ out) {
    long idx8 = (long)blockIdx.x * 256 + threadIdx.x;   // < 983040
    long row = idx8 >> 4;
    int seg = (int)(idx8 & 15) * 8;
    int m = (int)(row / KA), k = (int)(row % KA);
    int w = iw[m];
    int cb = ecb[0];
    int cid = w >> 8;
    bf16x8 rv = *(const bf16x8*)&r1h[row * CH + seg];
    bf16x8 mv = *(const bf16x8*)&mlph[row * CH + seg];
    float* dst = out + ((long)(w * PW + k)) * CH + seg;
    float4 o0, o1;
    float ot[8];
    #pragma unroll
    for (int t = 0; t < 8; ++t) {
        float xa = b2f((u16)mv[t]);
        if (cb) xa = 0.5f * xa + (0.5f / RPC) * csum[cid * CH + seg + t];
        ot[t] = b2f((u16)rv[t]) + xa * ls2[seg + t];
    }
    o0.x = ot[0]; o0.y = ot[1]; o0.z = ot[2]; o0.w = ot[3];
    o1.x = ot[4]; o1.y = ot[5]; o1.z = ot[6]; o1.w = ot[7];
    *(float4*)dst = o0;
    *(float4*)(dst + 4) = o1;
}

extern "C" void kernel_launch(void* const* d_in, const int* in_sizes, int n_in,
                              void* d_out, int out_size, void* d_ws, size_t ws_size,
                              hipStream_t stream) {
    const float* x      = (const float*)d_in[0];
    const float* n1g    = (const float*)d_in[1];
    const float* n1b    = (const float*)d_in[2];
    const float* n2g    = (const float*)d_in[3];
    const float* n2b    = (const float*)d_in[4];
    const float* qkv_w  = (const float*)d_in[5];
    const float* qkv_b  = (const float*)d_in[6];
    const float* proj_w = (const float*)d_in[7];
    const float* proj_b = (const float*)d_in[8];
    const float* ls1    = (const float*)d_in[9];
    const float* ls2    = (const float*)d_in[10];
    const float* glu_w  = (const float*)d_in[11];
    const float* glu_b  = (const float*)d_in[12];
    const float* out_w  = (const float*)d_in[13];
    const float* out_b  = (const float*)d_in[14];
    const int*   iw     = (const int*)d_in[15];
    const int*   ecb    = (const int*)d_in[21];
    float* out = (float*)d_out;

    char* w = (char*)d_ws;
    u16*   s1h  = (u16*)w;                          // 15,728,640
    u16*   qkvb = (u16*)(w + 15728640);             // 47,185,920 ; act aliases
    u16*   act  = qkvb;                             // (dead after k_attn)
    u16*   obuf = (u16*)(w + 62914560);             // 15,728,640
    u16*   r1h  = (u16*)(w + 78643200);             // 15,728,640
    u16*   hbuf = (u16*)(w + 94371840);             // 15,728,640
    u16*   mlph = (u16*)(w + 110100480);            // 15,728,640
    u16*   wq   = (u16*)(w + 125829120);            // 49152 u16
    u16*   wp   = wq + 384 * 128;                   // 16384 u16
    u16*   wg   = wp + 128 * 128;                   // 81920 u16
    u16*   wo   = wg + 640 * 128;                   // 40960 u16
    float* csum = (float*)(w + 125829120 + 376832);

    k_cvt<<<(188416 + 255) / 256, 256, 0, stream>>>(qkv_w, proj_w, glu_w, out_w, wq, wp, wg, wo);
    hipMemsetAsync(csum, 0, 8 * CH * sizeof(float), stream);

    k_ln1 <<<N_WIN * PW / 8, 256, 0, stream>>>(x, n1g, n1b, out);
    k_ln2a<<<NTOK / 8, 256, 0, stream>>>(out, n2g, n2b, iw, s1h);
    k_qkv <<<NTOK / 64, 256, 0, stream>>>(s1h, wq, qkv_b, qkvb);
    k_attn<<<MSEL, 256, 0, stream>>>(qkvb, obuf);
    k_proj<<<NTOK / 64, 256, 0, stream>>>(obuf, wp, proj_b, s1h, ls1, n2g, n2b, r1h, hbuf);
    k_glu <<<NTOK / 64, 256, 0, stream>>>(hbuf, wg, glu_b, act);
    k_out <<<NTOK / 64, 256, 0, stream>>>(act, wo, out_b, mlph);
    k_csum<<<NTOK / 256, 256, 0, stream>>>(mlph, iw, csum);
    k_final<<<(NTOK * CH / 8) / 256, 256, 0, stream>>>(r1h, mlph, csum, ls2, iw, ecb, out);
    (void)in_sizes; (void)n_in; (void)out_size; (void)ws_size;
}

// Round 7
// 225.871 us; speedup vs baseline: 1.5434x; 1.0833x over previous
//
#include <hip/hip_runtime.h>
#include <math.h>

typedef unsigned short u16;
typedef unsigned int   u32;
typedef __attribute__((ext_vector_type(8))) short bf16x8;
typedef __attribute__((ext_vector_type(4))) float f32x4;

#define N_WIN 2048
#define PW    64
#define KA    40
#define MSEL  1536
#define CH    128
#define NH    4
#define GLUI  320
#define NTOK  (MSEL*KA)          // 61440
#define RPC   16384              // rows per chunk (CB mean)

__device__ __forceinline__ u16 f2b(float f) {
    u32 u = __float_as_uint(f);
    return (u16)((u + 0x7FFFu + ((u >> 16) & 1u)) >> 16);
}
__device__ __forceinline__ float b2f(u16 v) { return __uint_as_float(((u32)v) << 16); }

// fast GELU (tanh form, max abs err ~3e-4; below bf16 act quantization)
__device__ __forceinline__ float fgelu(float g) {
    float x2 = g * g;
    float t = 1.5957691216f * g * (1.f + 0.044715f * x2);  // 2*sqrt(2/pi)*(g+0.044715 g^3)
    float e = __expf(t);
    float th = 1.f - 2.f / (e + 1.f);                      // tanh(t/2 * 2) = tanh(arg)
    return 0.5f * g * (1.f + th);
}

// ---------------- all weights fp32 -> bf16 transposed, one launch -----------
__global__ __launch_bounds__(256) void k_cvt(const float* __restrict__ qkv_w,
                                             const float* __restrict__ proj_w,
                                             const float* __restrict__ glu_w,
                                             const float* __restrict__ out_w,
                                             u16* __restrict__ wq, u16* __restrict__ wp,
                                             u16* __restrict__ wg, u16* __restrict__ wo) {
    int idx = blockIdx.x * 256 + threadIdx.x;
    if (idx < 49152) {
        int n = idx / 128, k = idx % 128;
        wq[idx] = f2b(qkv_w[k * 384 + n]);
    } else if (idx < 65536) {
        int i = idx - 49152, n = i / 128, k = i % 128;
        wp[i] = f2b(proj_w[k * 128 + n]);
    } else if (idx < 147456) {
        int i = idx - 65536, n = i / 128, k = i % 128;
        wg[i] = f2b(glu_w[k * 640 + n]);
    } else if (idx < 188416) {
        int i = idx - 147456, n = i / 320, k = i % 320;
        wo[i] = f2b(out_w[k * 128 + n]);
    }
}

// ---------------- LN1 over all 131072 rows -> d_out -------------------------
__global__ __launch_bounds__(256) void k_ln1(const float* __restrict__ x,
                                             const float* __restrict__ g,
                                             const float* __restrict__ b,
                                             float* __restrict__ out) {
    int wave = threadIdx.x >> 6, lane = threadIdx.x & 63;
    long row = (long)blockIdx.x * 8 + wave * 2 + (lane >> 5);
    int col = (lane & 31) * 4;
    float4 v = *(const float4*)(x + row * CH + col);
    float s  = v.x + v.y + v.z + v.w;
    float s2 = v.x * v.x + v.y * v.y + v.z * v.z + v.w * v.w;
    #pragma unroll
    for (int o = 16; o; o >>= 1) { s += __shfl_xor(s, o); s2 += __shfl_xor(s2, o); }
    float mu = s * (1.f / CH), var = s2 * (1.f / CH) - mu * mu;
    float r = rsqrtf(var + 1e-5f);
    float4 gg = *(const float4*)(g + col);
    float4 bb = *(const float4*)(b + col);
    float4 o4;
    o4.x = (v.x - mu) * r * gg.x + bb.x;
    o4.y = (v.y - mu) * r * gg.y + bb.y;
    o4.z = (v.z - mu) * r * gg.z + bb.z;
    o4.w = (v.w - mu) * r * gg.w + bb.w;
    *(float4*)(out + row * CH + col) = o4;
}

// ---------------- gather + LN2 -> s1h bf16 ----------------------------------
__global__ __launch_bounds__(256) void k_ln2a(const float* __restrict__ ln1,
                                              const float* __restrict__ g2,
                                              const float* __restrict__ b2,
                                              const int* __restrict__ iw,
                                              u16* __restrict__ s1h) {
    int wave = threadIdx.x >> 6, lane = threadIdx.x & 63;
    long row = (long)blockIdx.x * 8 + wave * 2 + (lane >> 5);   // < 61440
    int col = (lane & 31) * 4;
    int m = (int)(row / KA), r = (int)(row % KA);
    const float* src = ln1 + ((long)iw[m] * PW + r) * CH + col;
    float4 v = *(const float4*)src;
    float s  = v.x + v.y + v.z + v.w;
    float s2 = v.x * v.x + v.y * v.y + v.z * v.z + v.w * v.w;
    #pragma unroll
    for (int o = 16; o; o >>= 1) { s += __shfl_xor(s, o); s2 += __shfl_xor(s2, o); }
    float mu = s * (1.f / CH), var = s2 * (1.f / CH) - mu * mu;
    float rr = rsqrtf(var + 1e-5f);
    float4 gg = *(const float4*)(g2 + col);
    float4 bb = *(const float4*)(b2 + col);
    ushort4 o4;
    o4.x = f2b((v.x - mu) * rr * gg.x + bb.x);
    o4.y = f2b((v.y - mu) * rr * gg.y + bb.y);
    o4.z = f2b((v.z - mu) * rr * gg.z + bb.z);
    o4.w = f2b((v.w - mu) * rr * gg.w + bb.w);
    *(ushort4*)(s1h + row * CH + col) = o4;
}

// ---------------- QKV GEMM: j-outer, persistent A-frags ---------------------
__global__ __launch_bounds__(256, 3) void k_qkv(const u16* __restrict__ A,
                                                const u16* __restrict__ wq,
                                                const float* __restrict__ qkv_b,
                                                u16* __restrict__ qkvb) {
    __shared__ u16 Al[64][136];
    int tid = threadIdx.x, wid = tid >> 6, lane = tid & 63;
    int l15 = lane & 15, lg = lane >> 4;
    long m0 = (long)blockIdx.x * 64;
    #pragma unroll
    for (int ch = 0; ch < 4; ++ch) {
        int id = tid + ch * 256; int row = id >> 4, c8 = id & 15;
        *(bf16x8*)&Al[row][c8 * 8] = *(const bf16x8*)&A[(m0 + row) * CH + c8 * 8];
    }
    __syncthreads();
    bf16x8 af[4][4];
    #pragma unroll
    for (int st = 0; st < 4; ++st)
        #pragma unroll
        for (int ks = 0; ks < 4; ++ks)
            af[st][ks] = *(const bf16x8*)&Al[st * 16 + l15][ks * 32 + lg * 8];
    #pragma unroll
    for (int j = 0; j < 6; ++j) {
        int col = wid * 96 + j * 16 + l15;
        bf16x8 bf[4];
        #pragma unroll
        for (int ks = 0; ks < 4; ++ks)
            bf[ks] = *(const bf16x8*)&wq[(long)col * CH + ks * 32 + lg * 8];
        f32x4 acc[4] = {};
        #pragma unroll
        for (int ks = 0; ks < 4; ++ks)
            #pragma unroll
            for (int st = 0; st < 4; ++st)
                acc[st] = __builtin_amdgcn_mfma_f32_16x16x32_bf16(af[st][ks], bf[ks], acc[st], 0, 0, 0);
        float bc = qkv_b[col];
        #pragma unroll
        for (int st = 0; st < 4; ++st)
            #pragma unroll
            for (int r = 0; r < 4; ++r)
                qkvb[(m0 + st * 16 + lg * 4 + r) * 384 + col] = f2b(acc[st][r] + bc);
    }
}

// ---------------- per-window MFMA attention (R3-proven form) -----------------
__global__ __launch_bounds__(256) void k_attn(const u16* __restrict__ qkvb,
                                              u16* __restrict__ obuf) {
    __shared__ u16 qk[KA][392];
    __shared__ u16 vT[NH][32][72];
    int m = blockIdx.x, tid = threadIdx.x;
    int h = tid >> 6, lane = tid & 63, l15 = lane & 15, lg = lane >> 4;

    for (int i = tid; i < KA * 48; i += 256) {
        int j = i / 48, seg = i % 48;
        *(bf16x8*)&qk[j][seg * 8] = *(const bf16x8*)&qkvb[((long)m * KA + j) * 384 + seg * 8];
    }
    __syncthreads();
    for (int i = tid; i < NH * 32 * 64; i += 256) {
        int hh = i / (32 * 64), rem = i % (32 * 64), d = rem / 64, j = rem % 64;
        vT[hh][d][j] = (j < KA) ? qk[j][hh * 96 + 64 + d] : (u16)0;
    }
    __syncthreads();

    bf16x8 aq[3], bk[3];
    #pragma unroll
    for (int t = 0; t < 3; ++t) {
        int rr = t * 16 + l15; if (rr > KA - 1) rr = KA - 1;
        aq[t] = *(const bf16x8*)&qk[rr][h * 96 + lg * 8];
        bk[t] = *(const bf16x8*)&qk[rr][h * 96 + 32 + lg * 8];
    }
    f32x4 zero = {};
    f32x4 s[3][3];
    #pragma unroll
    for (int mi = 0; mi < 3; ++mi)
        #pragma unroll
        for (int ni = 0; ni < 3; ++ni)
            s[mi][ni] = __builtin_amdgcn_mfma_f32_16x16x32_bf16(aq[mi], bk[ni], zero, 0, 0, 0);

    const float scale = 0.17677669529663687f;
    float inv_[3][4];
    #pragma unroll
    for (int mi = 0; mi < 3; ++mi)
        #pragma unroll
        for (int r = 0; r < 4; ++r) {
            float v0 = s[mi][0][r] * scale;
            float v1 = s[mi][1][r] * scale;
            float v2 = (l15 >= 8) ? -1e30f : s[mi][2][r] * scale;   // mask keys >= 40
            float mx = fmaxf(fmaxf(v0, v1), v2);
            #pragma unroll
            for (int o = 1; o < 16; o <<= 1) mx = fmaxf(mx, __shfl_xor(mx, o));
            float e0 = __expf(v0 - mx), e1 = __expf(v1 - mx), e2 = __expf(v2 - mx);
            float sm = e0 + e1 + e2;
            #pragma unroll
            for (int o = 1; o < 16; o <<= 1) sm += __shfl_xor(sm, o);
            inv_[mi][r] = 1.f / sm;
            int row = mi * 16 + lg * 4 + r;
            if (row < KA) {
                qk[row][h * 96 + l15]      = f2b(e0);
                qk[row][h * 96 + 16 + l15] = f2b(e1);
                qk[row][h * 96 + 32 + l15] = f2b(e2);
            }
        }

    f32x4 o[3][2] = {};
    #pragma unroll
    for (int ks = 0; ks < 2; ++ks) {
        bf16x8 pa[3], vb[2];
        #pragma unroll
        for (int mi = 0; mi < 3; ++mi) {
            int rp = mi * 16 + l15; if (rp > KA - 1) rp = KA - 1;
            pa[mi] = *(const bf16x8*)&qk[rp][h * 96 + ks * 32 + lg * 8];
        }
        #pragma unroll
        for (int nf = 0; nf < 2; ++nf) vb[nf] = *(const bf16x8*)&vT[h][nf * 16 + l15][ks * 32 + lg * 8];
        #pragma unroll
        for (int mi = 0; mi < 3; ++mi)
            #pragma unroll
            for (int nf = 0; nf < 2; ++nf)
                o[mi][nf] = __builtin_amdgcn_mfma_f32_16x16x32_bf16(pa[mi], vb[nf], o[mi][nf], 0, 0, 0);
    }
    #pragma unroll
    for (int mi = 0; mi < 3; ++mi)
        #pragma unroll
        for (int nf = 0; nf < 2; ++nf)
            #pragma unroll
            for (int r = 0; r < 4; ++r) {
                int row4 = mi * 16 + lg * 4 + r;
                if (row4 < KA)
                    obuf[((long)m * KA + row4) * CH + h * 32 + nf * 16 + l15] =
                        f2b(o[mi][nf][r] * inv_[mi][r]);
            }
}

// ---------------- proj: reg-B + LDS-A + residual + LN2 (cross-wave) ---------
__global__ __launch_bounds__(256, 3) void k_proj(const u16* __restrict__ obuf,
                                                 const u16* __restrict__ wp,
                                                 const float* __restrict__ proj_b,
                                                 const u16* __restrict__ s1h,
                                                 const float* __restrict__ ls1,
                                                 const float* __restrict__ g2,
                                                 const float* __restrict__ b2,
                                                 u16* __restrict__ r1h,
                                                 u16* __restrict__ hbuf) {
    __shared__ u16 Al[64][136];
    __shared__ float ps[4][64], ps2[4][64];
    int tid = threadIdx.x, wid = tid >> 6, lane = tid & 63;
    int l15 = lane & 15, lg = lane >> 4;
    long m0 = (long)blockIdx.x * 64;
    bf16x8 bf[2][4];
    #pragma unroll
    for (int j = 0; j < 2; ++j)
        #pragma unroll
        for (int ks = 0; ks < 4; ++ks)
            bf[j][ks] = *(const bf16x8*)&wp[(long)(wid * 32 + j * 16 + l15) * CH + ks * 32 + lg * 8];
    #pragma unroll
    for (int ch = 0; ch < 4; ++ch) {
        int id = tid + ch * 256; int row = id >> 4, c8 = id & 15;
        *(bf16x8*)&Al[row][c8 * 8] = *(const bf16x8*)&obuf[(m0 + row) * CH + c8 * 8];
    }
    __syncthreads();
    float vals[4][2][4];
    #pragma unroll
    for (int st = 0; st < 4; ++st) {
        bf16x8 af[4];
        #pragma unroll
        for (int ks = 0; ks < 4; ++ks) af[ks] = *(const bf16x8*)&Al[st * 16 + l15][ks * 32 + lg * 8];
        f32x4 acc[2] = {};
        #pragma unroll
        for (int ks = 0; ks < 4; ++ks)
            #pragma unroll
            for (int j = 0; j < 2; ++j)
                acc[j] = __builtin_amdgcn_mfma_f32_16x16x32_bf16(af[ks], bf[j][ks], acc[j], 0, 0, 0);
        #pragma unroll
        for (int r = 0; r < 4; ++r) {
            long row = m0 + st * 16 + lg * 4 + r;
            float s = 0.f, s2 = 0.f;
            #pragma unroll
            for (int j = 0; j < 2; ++j) {
                int col = wid * 32 + j * 16 + l15;
                float v = acc[j][r] + proj_b[col];
                v = b2f(s1h[row * CH + col]) + v * ls1[col];
                vals[st][j][r] = v; s += v; s2 += v * v;
            }
            #pragma unroll
            for (int msk = 1; msk < 16; msk <<= 1) { s += __shfl_xor(s, msk); s2 += __shfl_xor(s2, msk); }
            if (l15 == 0) {
                ps[wid][st * 16 + lg * 4 + r]  = s;
                ps2[wid][st * 16 + lg * 4 + r] = s2;
            }
        }
    }
    __syncthreads();
    #pragma unroll
    for (int st = 0; st < 4; ++st)
        #pragma unroll
        for (int r = 0; r < 4; ++r) {
            int rl = st * 16 + lg * 4 + r;
            long row = m0 + rl;
            float s  = ps[0][rl] + ps[1][rl] + ps[2][rl] + ps[3][rl];
            float s2 = ps2[0][rl] + ps2[1][rl] + ps2[2][rl] + ps2[3][rl];
            float mu = s * (1.f / CH), var = s2 * (1.f / CH) - mu * mu;
            float rr = rsqrtf(var + 1e-5f);
            #pragma unroll
            for (int j = 0; j < 2; ++j) {
                int col = wid * 32 + j * 16 + l15;
                float v = vals[st][j][r];
                r1h[row * CH + col]  = f2b(v);
                hbuf[row * CH + col] = f2b((v - mu) * rr * g2[col] + b2[col]);
            }
        }
}

// ---------------- GLU: j-outer, persistent A-frags, fast gelu ---------------
__global__ __launch_bounds__(256, 3) void k_glu(const u16* __restrict__ hbuf,
                                                const u16* __restrict__ wg,
                                                const float* __restrict__ glu_b,
                                                u16* __restrict__ act) {
    __shared__ u16 Al[64][136];
    int tid = threadIdx.x, wid = tid >> 6, lane = tid & 63;
    int l15 = lane & 15, lg = lane >> 4;
    long m0 = (long)blockIdx.x * 64;
    #pragma unroll
    for (int ch = 0; ch < 4; ++ch) {
        int id = tid + ch * 256; int row = id >> 4, c8 = id & 15;
        *(bf16x8*)&Al[row][c8 * 8] = *(const bf16x8*)&hbuf[(m0 + row) * CH + c8 * 8];
    }
    __syncthreads();
    bf16x8 af[4][4];
    #pragma unroll
    for (int st = 0; st < 4; ++st)
        #pragma unroll
        for (int ks = 0; ks < 4; ++ks)
            af[st][ks] = *(const bf16x8*)&Al[st * 16 + l15][ks * 32 + lg * 8];
    #pragma unroll
    for (int j = 0; j < 5; ++j) {
        int col = wid * 80 + j * 16 + l15;
        bf16x8 bu[4], bg[4];
        #pragma unroll
        for (int ks = 0; ks < 4; ++ks) {
            bu[ks] = *(const bf16x8*)&wg[(long)col * CH + ks * 32 + lg * 8];
            bg[ks] = *(const bf16x8*)&wg[(long)(col + GLUI) * CH + ks * 32 + lg * 8];
        }
        f32x4 au[4] = {}, ag[4] = {};
        #pragma unroll
        for (int ks = 0; ks < 4; ++ks)
            #pragma unroll
            for (int st = 0; st < 4; ++st) {
                au[st] = __builtin_amdgcn_mfma_f32_16x16x32_bf16(af[st][ks], bu[ks], au[st], 0, 0, 0);
                ag[st] = __builtin_amdgcn_mfma_f32_16x16x32_bf16(af[st][ks], bg[ks], ag[st], 0, 0, 0);
            }
        float bu_ = glu_b[col], bg_ = glu_b[col + GLUI];
        #pragma unroll
        for (int st = 0; st < 4; ++st)
            #pragma unroll
            for (int r = 0; r < 4; ++r) {
                long row = m0 + st * 16 + lg * 4 + r;
                float uu = au[st][r] + bu_;
                float gg = ag[st][r] + bg_;
                act[row * GLUI + col] = f2b(uu * fgelu(gg));
            }
    }
}

// ---------------- OUT: j-outer, A staged in LDS (K=320) ---------------------
__global__ __launch_bounds__(256, 3) void k_out(const u16* __restrict__ act,
                                                const u16* __restrict__ wo,
                                                const float* __restrict__ out_b,
                                                u16* __restrict__ mlph) {
    __shared__ u16 Al[64][328];
    int tid = threadIdx.x, wid = tid >> 6, lane = tid & 63;
    int l15 = lane & 15, lg = lane >> 4;
    long m0 = (long)blockIdx.x * 64;
    #pragma unroll
    for (int ch = 0; ch < 10; ++ch) {
        int id = tid + ch * 256; int row = id / 40, c8 = id % 40;
        *(bf16x8*)&Al[row][c8 * 8] = *(const bf16x8*)&act[(m0 + row) * GLUI + c8 * 8];
    }
    __syncthreads();
    #pragma unroll
    for (int j = 0; j < 2; ++j) {
        int col = wid * 32 + j * 16 + l15;
        bf16x8 bo[10];
        #pragma unroll
        for (int ks = 0; ks < 10; ++ks)
            bo[ks] = *(const bf16x8*)&wo[(long)col * GLUI + ks * 32 + lg * 8];
        f32x4 acc[4] = {};
        #pragma unroll
        for (int ks = 0; ks < 10; ++ks)
            #pragma unroll
            for (int st = 0; st < 4; ++st) {
                bf16x8 af = *(const bf16x8*)&Al[st * 16 + l15][ks * 32 + lg * 8];
                acc[st] = __builtin_amdgcn_mfma_f32_16x16x32_bf16(af, bo[ks], acc[st], 0, 0, 0);
            }
        float bc = out_b[col];
        #pragma unroll
        for (int st = 0; st < 4; ++st)
            #pragma unroll
            for (int r = 0; r < 4; ++r)
                mlph[(m0 + st * 16 + lg * 4 + r) * CH + col] = f2b(acc[st][r] + bc);
    }
}

// ---------------- chunk sums of mlp (bf16) for the CB mean ------------------
__global__ __launch_bounds__(256) void k_csum(const u16* __restrict__ mlph,
                                              const int* __restrict__ iw,
                                              float* __restrict__ csum) {
    __shared__ float acc[2][8][CH];
    int tid = threadIdx.x, c = tid & 127, half = tid >> 7;
    #pragma unroll
    for (int i = 0; i < 8; ++i) acc[half][i][c] = 0.f;
    int base = blockIdx.x * 256;
    for (int r = base + half; r < base + 256; r += 2) {
        int cid = iw[r / KA] >> 8;
        acc[half][cid][c] += b2f(mlph[(long)r * CH + c]);
    }
    __syncthreads();
    if (half == 0)
        #pragma unroll
        for (int i = 0; i < 8; ++i)
            atomicAdd(&csum[i * CH + c], acc[0][i][c] + acc[1][i][c]);
}

// ---------------- finalize + scatter (8 cols/thread) ------------------------
__global__ __launch_bounds__(256) void k_final(const u16* __restrict__ r1h,
                                               const u16* __restrict__ mlph,
                                               const float* __restrict__ csum,
                                               const float* __restrict__ ls2,
                                               const int* __restrict__ iw,
                                               const int* __restrict__ ecb,
                                               float* __restrict__ out) {
    long idx8 = (long)blockIdx.x * 256 + threadIdx.x;   // < 983040
    long row = idx8 >> 4;
    int seg = (int)(idx8 & 15) * 8;
    int m = (int)(row / KA), k = (int)(row % KA);
    int w = iw[m];
    int cb = ecb[0];
    int cid = w >> 8;
    bf16x8 rv = *(const bf16x8*)&r1h[row * CH + seg];
    bf16x8 mv = *(const bf16x8*)&mlph[row * CH + seg];
    float* dst = out + ((long)(w * PW + k)) * CH + seg;
    float4 o0, o1;
    float ot[8];
    #pragma unroll
    for (int t = 0; t < 8; ++t) {
        float xa = b2f((u16)mv[t]);
        if (cb) xa = 0.5f * xa + (0.5f / RPC) * csum[cid * CH + seg + t];
        ot[t] = b2f((u16)rv[t]) + xa * ls2[seg + t];
    }
    o0.x = ot[0]; o0.y = ot[1]; o0.z = ot[2]; o0.w = ot[3];
    o1.x = ot[4]; o1.y = ot[5]; o1.z = ot[6]; o1.w = ot[7];
    *(float4*)dst = o0;
    *(float4*)(dst + 4) = o1;
}

extern "C" void kernel_launch(void* const* d_in, const int* in_sizes, int n_in,
                              void* d_out, int out_size, void* d_ws, size_t ws_size,
                              hipStream_t stream) {
    const float* x      = (const float*)d_in[0];
    const float* n1g    = (const float*)d_in[1];
    const float* n1b    = (const float*)d_in[2];
    const float* n2g    = (const float*)d_in[3];
    const float* n2b    = (const float*)d_in[4];
    const float* qkv_w  = (const float*)d_in[5];
    const float* qkv_b  = (const float*)d_in[6];
    const float* proj_w = (const float*)d_in[7];
    const float* proj_b = (const float*)d_in[8];
    const float* ls1    = (const float*)d_in[9];
    const float* ls2    = (const float*)d_in[10];
    const float* glu_w  = (const float*)d_in[11];
    const float* glu_b  = (const float*)d_in[12];
    const float* out_w  = (const float*)d_in[13];
    const float* out_b  = (const float*)d_in[14];
    const int*   iw     = (const int*)d_in[15];
    const int*   ecb    = (const int*)d_in[21];
    float* out = (float*)d_out;

    char* w = (char*)d_ws;
    u16*   s1h  = (u16*)w;                          // 15,728,640
    u16*   qkvb = (u16*)(w + 15728640);             // 47,185,920 ; act aliases
    u16*   act  = qkvb;                             // (dead after k_attn)
    u16*   obuf = (u16*)(w + 62914560);             // 15,728,640
    u16*   r1h  = (u16*)(w + 78643200);             // 15,728,640
    u16*   hbuf = (u16*)(w + 94371840);             // 15,728,640
    u16*   mlph = (u16*)(w + 110100480);            // 15,728,640
    u16*   wq   = (u16*)(w + 125829120);            // 49152 u16
    u16*   wp   = wq + 384 * 128;                   // 16384 u16
    u16*   wg   = wp + 128 * 128;                   // 81920 u16
    u16*   wo   = wg + 640 * 128;                   // 40960 u16
    float* csum = (float*)(w + 125829120 + 376832);

    k_cvt<<<(188416 + 255) / 256, 256, 0, stream>>>(qkv_w, proj_w, glu_w, out_w, wq, wp, wg, wo);
    hipMemsetAsync(csum, 0, 8 * CH * sizeof(float), stream);

    k_ln1 <<<N_WIN * PW / 8, 256, 0, stream>>>(x, n1g, n1b, out);
    k_ln2a<<<NTOK / 8, 256, 0, stream>>>(out, n2g, n2b, iw, s1h);
    k_qkv <<<NTOK / 64, 256, 0, stream>>>(s1h, wq, qkv_b, qkvb);
    k_attn<<<MSEL, 256, 0, stream>>>(qkvb, obuf);
    k_proj<<<NTOK / 64, 256, 0, stream>>>(obuf, wp, proj_b, s1h, ls1, n2g, n2b, r1h, hbuf);
    k_glu <<<NTOK / 64, 256, 0, stream>>>(hbuf, wg, glu_b, act);
    k_out <<<NTOK / 64, 256, 0, stream>>>(act, wo, out_b, mlph);
    k_csum<<<NTOK / 256, 256, 0, stream>>>(mlph, iw, csum);
    k_final<<<(NTOK * CH / 8) / 256, 256, 0, stream>>>(r1h, mlph, csum, ls2, iw, ecb, out);
    (void)in_sizes; (void)n_in; (void)out_size; (void)ws_size;
}

// Round 8
// 221.394 us; speedup vs baseline: 1.5746x; 1.0202x over previous
//
#include <hip/hip_runtime.h>
#include <math.h>

typedef unsigned short u16;
typedef unsigned int   u32;
typedef __attribute__((ext_vector_type(8))) short bf16x8;
typedef __attribute__((ext_vector_type(4))) float f32x4;

#define N_WIN 2048
#define PW    64
#define KA    40
#define MSEL  1536
#define CH    128
#define NH    4
#define GLUI  320
#define NTOK  (MSEL*KA)          // 61440
#define RPC   16384              // rows per chunk (CB mean)

__device__ __forceinline__ u16 f2b(float f) {
    u32 u = __float_as_uint(f);
    return (u16)((u + 0x7FFFu + ((u >> 16) & 1u)) >> 16);
}
__device__ __forceinline__ float b2f(u16 v) { return __uint_as_float(((u32)v) << 16); }

// fast GELU (tanh form, max abs err ~3e-4; below bf16 act quantization)
__device__ __forceinline__ float fgelu(float g) {
    float x2 = g * g;
    float t = 1.5957691216f * g * (1.f + 0.044715f * x2);
    float e = __expf(t);
    float th = 1.f - 2.f / (e + 1.f);
    return 0.5f * g * (1.f + th);
}

// ---------------- all weights fp32 -> bf16 transposed, one launch -----------
__global__ __launch_bounds__(256) void k_cvt(const float* __restrict__ qkv_w,
                                             const float* __restrict__ proj_w,
                                             const float* __restrict__ glu_w,
                                             const float* __restrict__ out_w,
                                             u16* __restrict__ wq, u16* __restrict__ wp,
                                             u16* __restrict__ wg, u16* __restrict__ wo) {
    int idx = blockIdx.x * 256 + threadIdx.x;
    if (idx < 49152) {
        int n = idx / 128, k = idx % 128;
        wq[idx] = f2b(qkv_w[k * 384 + n]);
    } else if (idx < 65536) {
        int i = idx - 49152, n = i / 128, k = i % 128;
        wp[i] = f2b(proj_w[k * 128 + n]);
    } else if (idx < 147456) {
        int i = idx - 65536, n = i / 128, k = i % 128;
        wg[i] = f2b(glu_w[k * 640 + n]);
    } else if (idx < 188416) {
        int i = idx - 147456, n = i / 320, k = i % 320;
        wo[i] = f2b(out_w[k * 128 + n]);
    }
}

// ---------------- LN1 over all 131072 rows -> d_out -------------------------
__global__ __launch_bounds__(256) void k_ln1(const float* __restrict__ x,
                                             const float* __restrict__ g,
                                             const float* __restrict__ b,
                                             float* __restrict__ out) {
    int wave = threadIdx.x >> 6, lane = threadIdx.x & 63;
    long row = (long)blockIdx.x * 8 + wave * 2 + (lane >> 5);
    int col = (lane & 31) * 4;
    float4 v = *(const float4*)(x + row * CH + col);
    float s  = v.x + v.y + v.z + v.w;
    float s2 = v.x * v.x + v.y * v.y + v.z * v.z + v.w * v.w;
    #pragma unroll
    for (int o = 16; o; o >>= 1) { s += __shfl_xor(s, o); s2 += __shfl_xor(s2, o); }
    float mu = s * (1.f / CH), var = s2 * (1.f / CH) - mu * mu;
    float r = rsqrtf(var + 1e-5f);
    float4 gg = *(const float4*)(g + col);
    float4 bb = *(const float4*)(b + col);
    float4 o4;
    o4.x = (v.x - mu) * r * gg.x + bb.x;
    o4.y = (v.y - mu) * r * gg.y + bb.y;
    o4.z = (v.z - mu) * r * gg.z + bb.z;
    o4.w = (v.w - mu) * r * gg.w + bb.w;
    *(float4*)(out + row * CH + col) = o4;
}

// ---------------- gather + LN2 -> s1h bf16 ----------------------------------
__global__ __launch_bounds__(256) void k_ln2a(const float* __restrict__ ln1,
                                              const float* __restrict__ g2,
                                              const float* __restrict__ b2,
                                              const int* __restrict__ iw,
                                              u16* __restrict__ s1h) {
    int wave = threadIdx.x >> 6, lane = threadIdx.x & 63;
    long row = (long)blockIdx.x * 8 + wave * 2 + (lane >> 5);   // < 61440
    int col = (lane & 31) * 4;
    int m = (int)(row / KA), r = (int)(row % KA);
    const float* src = ln1 + ((long)iw[m] * PW + r) * CH + col;
    float4 v = *(const float4*)src;
    float s  = v.x + v.y + v.z + v.w;
    float s2 = v.x * v.x + v.y * v.y + v.z * v.z + v.w * v.w;
    #pragma unroll
    for (int o = 16; o; o >>= 1) { s += __shfl_xor(s, o); s2 += __shfl_xor(s2, o); }
    float mu = s * (1.f / CH), var = s2 * (1.f / CH) - mu * mu;
    float rr = rsqrtf(var + 1e-5f);
    float4 gg = *(const float4*)(g2 + col);
    float4 bb = *(const float4*)(b2 + col);
    ushort4 o4;
    o4.x = f2b((v.x - mu) * rr * gg.x + bb.x);
    o4.y = f2b((v.y - mu) * rr * gg.y + bb.y);
    o4.z = f2b((v.z - mu) * rr * gg.z + bb.z);
    o4.w = f2b((v.w - mu) * rr * gg.w + bb.w);
    *(ushort4*)(s1h + row * CH + col) = o4;
}

// ---------------- QKV GEMM: grid (960,3), wave owns 32 cols -----------------
__global__ __launch_bounds__(256, 4) void k_qkv(const u16* __restrict__ A,
                                                const u16* __restrict__ wq,
                                                const float* __restrict__ qkv_b,
                                                u16* __restrict__ qkvb) {
    __shared__ u16 Al[64][136];
    int tid = threadIdx.x, wid = tid >> 6, lane = tid & 63;
    int l15 = lane & 15, lg = lane >> 4;
    long m0 = (long)blockIdx.x * 64;
    int c0 = blockIdx.y * 128 + wid * 32;
    #pragma unroll
    for (int ch = 0; ch < 4; ++ch) {
        int id = tid + ch * 256; int row = id >> 4, c8 = id & 15;
        *(bf16x8*)&Al[row][c8 * 8] = *(const bf16x8*)&A[(m0 + row) * CH + c8 * 8];
    }
    bf16x8 bf[2][4];
    #pragma unroll
    for (int j = 0; j < 2; ++j)
        #pragma unroll
        for (int ks = 0; ks < 4; ++ks)
            bf[j][ks] = *(const bf16x8*)&wq[(long)(c0 + j * 16 + l15) * CH + ks * 32 + lg * 8];
    __syncthreads();
    f32x4 acc[2][4] = {};
    #pragma unroll
    for (int st = 0; st < 4; ++st)
        #pragma unroll
        for (int ks = 0; ks < 4; ++ks) {
            bf16x8 af = *(const bf16x8*)&Al[st * 16 + l15][ks * 32 + lg * 8];
            #pragma unroll
            for (int j = 0; j < 2; ++j)
                acc[j][st] = __builtin_amdgcn_mfma_f32_16x16x32_bf16(af, bf[j][ks], acc[j][st], 0, 0, 0);
        }
    #pragma unroll
    for (int j = 0; j < 2; ++j) {
        int col = c0 + j * 16 + l15;
        float bc = qkv_b[col];
        #pragma unroll
        for (int st = 0; st < 4; ++st)
            #pragma unroll
            for (int r = 0; r < 4; ++r)
                qkvb[(m0 + st * 16 + lg * 4 + r) * 384 + col] = f2b(acc[j][st][r] + bc);
    }
}

// ---------------- per-window MFMA attention (R3-proven form) -----------------
__global__ __launch_bounds__(256) void k_attn(const u16* __restrict__ qkvb,
                                              u16* __restrict__ obuf) {
    __shared__ u16 qk[KA][392];
    __shared__ u16 vT[NH][32][72];
    int m = blockIdx.x, tid = threadIdx.x;
    int h = tid >> 6, lane = tid & 63, l15 = lane & 15, lg = lane >> 4;

    for (int i = tid; i < KA * 48; i += 256) {
        int j = i / 48, seg = i % 48;
        *(bf16x8*)&qk[j][seg * 8] = *(const bf16x8*)&qkvb[((long)m * KA + j) * 384 + seg * 8];
    }
    __syncthreads();
    for (int i = tid; i < NH * 32 * 64; i += 256) {
        int hh = i / (32 * 64), rem = i % (32 * 64), d = rem / 64, j = rem % 64;
        vT[hh][d][j] = (j < KA) ? qk[j][hh * 96 + 64 + d] : (u16)0;
    }
    __syncthreads();

    bf16x8 aq[3], bk[3];
    #pragma unroll
    for (int t = 0; t < 3; ++t) {
        int rr = t * 16 + l15; if (rr > KA - 1) rr = KA - 1;
        aq[t] = *(const bf16x8*)&qk[rr][h * 96 + lg * 8];
        bk[t] = *(const bf16x8*)&qk[rr][h * 96 + 32 + lg * 8];
    }
    f32x4 zero = {};
    f32x4 s[3][3];
    #pragma unroll
    for (int mi = 0; mi < 3; ++mi)
        #pragma unroll
        for (int ni = 0; ni < 3; ++ni)
            s[mi][ni] = __builtin_amdgcn_mfma_f32_16x16x32_bf16(aq[mi], bk[ni], zero, 0, 0, 0);

    const float scale = 0.17677669529663687f;
    float inv_[3][4];
    #pragma unroll
    for (int mi = 0; mi < 3; ++mi)
        #pragma unroll
        for (int r = 0; r < 4; ++r) {
            float v0 = s[mi][0][r] * scale;
            float v1 = s[mi][1][r] * scale;
            float v2 = (l15 >= 8) ? -1e30f : s[mi][2][r] * scale;   // mask keys >= 40
            float mx = fmaxf(fmaxf(v0, v1), v2);
            #pragma unroll
            for (int o = 1; o < 16; o <<= 1) mx = fmaxf(mx, __shfl_xor(mx, o));
            float e0 = __expf(v0 - mx), e1 = __expf(v1 - mx), e2 = __expf(v2 - mx);
            float sm = e0 + e1 + e2;
            #pragma unroll
            for (int o = 1; o < 16; o <<= 1) sm += __shfl_xor(sm, o);
            inv_[mi][r] = 1.f / sm;
            int row = mi * 16 + lg * 4 + r;
            if (row < KA) {
                qk[row][h * 96 + l15]      = f2b(e0);
                qk[row][h * 96 + 16 + l15] = f2b(e1);
                qk[row][h * 96 + 32 + l15] = f2b(e2);
            }
        }

    f32x4 o[3][2] = {};
    #pragma unroll
    for (int ks = 0; ks < 2; ++ks) {
        bf16x8 pa[3], vb[2];
        #pragma unroll
        for (int mi = 0; mi < 3; ++mi) {
            int rp = mi * 16 + l15; if (rp > KA - 1) rp = KA - 1;
            pa[mi] = *(const bf16x8*)&qk[rp][h * 96 + ks * 32 + lg * 8];
        }
        #pragma unroll
        for (int nf = 0; nf < 2; ++nf) vb[nf] = *(const bf16x8*)&vT[h][nf * 16 + l15][ks * 32 + lg * 8];
        #pragma unroll
        for (int mi = 0; mi < 3; ++mi)
            #pragma unroll
            for (int nf = 0; nf < 2; ++nf)
                o[mi][nf] = __builtin_amdgcn_mfma_f32_16x16x32_bf16(pa[mi], vb[nf], o[mi][nf], 0, 0, 0);
    }
    #pragma unroll
    for (int mi = 0; mi < 3; ++mi)
        #pragma unroll
        for (int nf = 0; nf < 2; ++nf)
            #pragma unroll
            for (int r = 0; r < 4; ++r) {
                int row4 = mi * 16 + lg * 4 + r;
                if (row4 < KA)
                    obuf[((long)m * KA + row4) * CH + h * 32 + nf * 16 + l15] =
                        f2b(o[mi][nf][r] * inv_[mi][r]);
            }
}

// ---------------- proj: reg-B + LDS-A + residual + LN2 (cross-wave) ---------
__global__ __launch_bounds__(256, 3) void k_proj(const u16* __restrict__ obuf,
                                                 const u16* __restrict__ wp,
                                                 const float* __restrict__ proj_b,
                                                 const u16* __restrict__ s1h,
                                                 const float* __restrict__ ls1,
                                                 const float* __restrict__ g2,
                                                 const float* __restrict__ b2,
                                                 u16* __restrict__ r1h,
                                                 u16* __restrict__ hbuf) {
    __shared__ u16 Al[64][136];
    __shared__ float ps[4][64], ps2[4][64];
    int tid = threadIdx.x, wid = tid >> 6, lane = tid & 63;
    int l15 = lane & 15, lg = lane >> 4;
    long m0 = (long)blockIdx.x * 64;
    bf16x8 bf[2][4];
    #pragma unroll
    for (int j = 0; j < 2; ++j)
        #pragma unroll
        for (int ks = 0; ks < 4; ++ks)
            bf[j][ks] = *(const bf16x8*)&wp[(long)(wid * 32 + j * 16 + l15) * CH + ks * 32 + lg * 8];
    #pragma unroll
    for (int ch = 0; ch < 4; ++ch) {
        int id = tid + ch * 256; int row = id >> 4, c8 = id & 15;
        *(bf16x8*)&Al[row][c8 * 8] = *(const bf16x8*)&obuf[(m0 + row) * CH + c8 * 8];
    }
    __syncthreads();
    float vals[4][2][4];
    #pragma unroll
    for (int st = 0; st < 4; ++st) {
        bf16x8 af[4];
        #pragma unroll
        for (int ks = 0; ks < 4; ++ks) af[ks] = *(const bf16x8*)&Al[st * 16 + l15][ks * 32 + lg * 8];
        f32x4 acc[2] = {};
        #pragma unroll
        for (int ks = 0; ks < 4; ++ks)
            #pragma unroll
            for (int j = 0; j < 2; ++j)
                acc[j] = __builtin_amdgcn_mfma_f32_16x16x32_bf16(af[ks], bf[j][ks], acc[j], 0, 0, 0);
        #pragma unroll
        for (int r = 0; r < 4; ++r) {
            long row = m0 + st * 16 + lg * 4 + r;
            float s = 0.f, s2 = 0.f;
            #pragma unroll
            for (int j = 0; j < 2; ++j) {
                int col = wid * 32 + j * 16 + l15;
                float v = acc[j][r] + proj_b[col];
                v = b2f(s1h[row * CH + col]) + v * ls1[col];
                vals[st][j][r] = v; s += v; s2 += v * v;
            }
            #pragma unroll
            for (int msk = 1; msk < 16; msk <<= 1) { s += __shfl_xor(s, msk); s2 += __shfl_xor(s2, msk); }
            if (l15 == 0) {
                ps[wid][st * 16 + lg * 4 + r]  = s;
                ps2[wid][st * 16 + lg * 4 + r] = s2;
            }
        }
    }
    __syncthreads();
    #pragma unroll
    for (int st = 0; st < 4; ++st)
        #pragma unroll
        for (int r = 0; r < 4; ++r) {
            int rl = st * 16 + lg * 4 + r;
            long row = m0 + rl;
            float s  = ps[0][rl] + ps[1][rl] + ps[2][rl] + ps[3][rl];
            float s2 = ps2[0][rl] + ps2[1][rl] + ps2[2][rl] + ps2[3][rl];
            float mu = s * (1.f / CH), var = s2 * (1.f / CH) - mu * mu;
            float rr = rsqrtf(var + 1e-5f);
            #pragma unroll
            for (int j = 0; j < 2; ++j) {
                int col = wid * 32 + j * 16 + l15;
                float v = vals[st][j][r];
                r1h[row * CH + col]  = f2b(v);
                hbuf[row * CH + col] = f2b((v - mu) * rr * g2[col] + b2[col]);
            }
        }
}

// ---------------- GLU: grid (960,5), wave owns 16 col-pairs -----------------
__global__ __launch_bounds__(256, 4) void k_glu(const u16* __restrict__ hbuf,
                                                const u16* __restrict__ wg,
                                                const float* __restrict__ glu_b,
                                                u16* __restrict__ act) {
    __shared__ u16 Al[64][136];
    int tid = threadIdx.x, wid = tid >> 6, lane = tid & 63;
    int l15 = lane & 15, lg = lane >> 4;
    long m0 = (long)blockIdx.x * 64;
    int c0 = blockIdx.y * 64 + wid * 16;
    #pragma unroll
    for (int ch = 0; ch < 4; ++ch) {
        int id = tid + ch * 256; int row = id >> 4, c8 = id & 15;
        *(bf16x8*)&Al[row][c8 * 8] = *(const bf16x8*)&hbuf[(m0 + row) * CH + c8 * 8];
    }
    bf16x8 bu[4], bg[4];
    #pragma unroll
    for (int ks = 0; ks < 4; ++ks) {
        bu[ks] = *(const bf16x8*)&wg[(long)(c0 + l15) * CH + ks * 32 + lg * 8];
        bg[ks] = *(const bf16x8*)&wg[(long)(c0 + GLUI + l15) * CH + ks * 32 + lg * 8];
    }
    __syncthreads();
    f32x4 au[4] = {}, ag[4] = {};
    #pragma unroll
    for (int st = 0; st < 4; ++st)
        #pragma unroll
        for (int ks = 0; ks < 4; ++ks) {
            bf16x8 af = *(const bf16x8*)&Al[st * 16 + l15][ks * 32 + lg * 8];
            au[st] = __builtin_amdgcn_mfma_f32_16x16x32_bf16(af, bu[ks], au[st], 0, 0, 0);
            ag[st] = __builtin_amdgcn_mfma_f32_16x16x32_bf16(af, bg[ks], ag[st], 0, 0, 0);
        }
    int col = c0 + l15;
    float bu_ = glu_b[col], bg_ = glu_b[col + GLUI];
    #pragma unroll
    for (int st = 0; st < 4; ++st)
        #pragma unroll
        for (int r = 0; r < 4; ++r) {
            long row = m0 + st * 16 + lg * 4 + r;
            float uu = au[st][r] + bu_;
            float gg = ag[st][r] + bg_;
            act[row * GLUI + col] = f2b(uu * fgelu(gg));
        }
}

// ---------------- OUT: grid (960,2), wave owns 16 cols, B persistent --------
__global__ __launch_bounds__(256, 3) void k_out(const u16* __restrict__ act,
                                                const u16* __restrict__ wo,
                                                const float* __restrict__ out_b,
                                                u16* __restrict__ mlph) {
    __shared__ u16 Al[64][328];
    int tid = threadIdx.x, wid = tid >> 6, lane = tid & 63;
    int l15 = lane & 15, lg = lane >> 4;
    long m0 = (long)blockIdx.x * 64;
    int col = blockIdx.y * 64 + wid * 16 + l15;
    #pragma unroll
    for (int ch = 0; ch < 10; ++ch) {
        int id = tid + ch * 256; int row = id / 40, c8 = id % 40;
        *(bf16x8*)&Al[row][c8 * 8] = *(const bf16x8*)&act[(m0 + row) * GLUI + c8 * 8];
    }
    bf16x8 bo[10];
    #pragma unroll
    for (int ks = 0; ks < 10; ++ks)
        bo[ks] = *(const bf16x8*)&wo[(long)col * GLUI + ks * 32 + lg * 8];
    __syncthreads();
    f32x4 acc[4] = {};
    #pragma unroll
    for (int st = 0; st < 4; ++st)
        #pragma unroll
        for (int ks = 0; ks < 10; ++ks) {
            bf16x8 af = *(const bf16x8*)&Al[st * 16 + l15][ks * 32 + lg * 8];
            acc[st] = __builtin_amdgcn_mfma_f32_16x16x32_bf16(af, bo[ks], acc[st], 0, 0, 0);
        }
    float bc = out_b[col];
    #pragma unroll
    for (int st = 0; st < 4; ++st)
        #pragma unroll
        for (int r = 0; r < 4; ++r)
            mlph[(m0 + st * 16 + lg * 4 + r) * CH + col] = f2b(acc[st][r] + bc);
}

// ---------------- chunk sums of mlp (bf16) for the CB mean ------------------
__global__ __launch_bounds__(256) void k_csum(const u16* __restrict__ mlph,
                                              const int* __restrict__ iw,
                                              float* __restrict__ csum) {
    __shared__ float acc[2][8][CH];
    int tid = threadIdx.x, c = tid & 127, half = tid >> 7;
    #pragma unroll
    for (int i = 0; i < 8; ++i) acc[half][i][c] = 0.f;
    int base = blockIdx.x * 256;
    for (int r = base + half; r < base + 256; r += 2) {
        int cid = iw[r / KA] >> 8;
        acc[half][cid][c] += b2f(mlph[(long)r * CH + c]);
    }
    __syncthreads();
    if (half == 0)
        #pragma unroll
        for (int i = 0; i < 8; ++i)
            atomicAdd(&csum[i * CH + c], acc[0][i][c] + acc[1][i][c]);
}

// ---------------- finalize + scatter (8 cols/thread) ------------------------
__global__ __launch_bounds__(256) void k_final(const u16* __restrict__ r1h,
                                               const u16* __restrict__ mlph,
                                               const float* __restrict__ csum,
                                               const float* __restrict__ ls2,
                                               const int* __restrict__ iw,
                                               const int* __restrict__ ecb,
                                               float* __restrict__ out) {
    long idx8 = (long)blockIdx.x * 256 + threadIdx.x;   // < 983040
    long row = idx8 >> 4;
    int seg = (int)(idx8 & 15) * 8;
    int m = (int)(row / KA), k = (int)(row % KA);
    int w = iw[m];
    int cb = ecb[0];
    int cid = w >> 8;
    bf16x8 rv = *(const bf16x8*)&r1h[row * CH + seg];
    bf16x8 mv = *(const bf16x8*)&mlph[row * CH + seg];
    float* dst = out + ((long)(w * PW + k)) * CH + seg;
    float4 o0, o1;
    float ot[8];
    #pragma unroll
    for (int t = 0; t < 8; ++t) {
        float xa = b2f((u16)mv[t]);
        if (cb) xa = 0.5f * xa + (0.5f / RPC) * csum[cid * CH + seg + t];
        ot[t] = b2f((u16)rv[t]) + xa * ls2[seg + t];
    }
    o0.x = ot[0]; o0.y = ot[1]; o0.z = ot[2]; o0.w = ot[3];
    o1.x = ot[4]; o1.y = ot[5]; o1.z = ot[6]; o1.w = ot[7];
    *(float4*)dst = o0;
    *(float4*)(dst + 4) = o1;
}

extern "C" void kernel_launch(void* const* d_in, const int* in_sizes, int n_in,
                              void* d_out, int out_size, void* d_ws, size_t ws_size,
                              hipStream_t stream) {
    const float* x      = (const float*)d_in[0];
    const float* n1g    = (const float*)d_in[1];
    const float* n1b    = (const float*)d_in[2];
    const float* n2g    = (const float*)d_in[3];
    const float* n2b    = (const float*)d_in[4];
    const float* qkv_w  = (const float*)d_in[5];
    const float* qkv_b  = (const float*)d_in[6];
    const float* proj_w = (const float*)d_in[7];
    const float* proj_b = (const float*)d_in[8];
    const float* ls1    = (const float*)d_in[9];
    const float* ls2    = (const float*)d_in[10];
    const float* glu_w  = (const float*)d_in[11];
    const float* glu_b  = (const float*)d_in[12];
    const float* out_w  = (const float*)d_in[13];
    const float* out_b  = (const float*)d_in[14];
    const int*   iw     = (const int*)d_in[15];
    const int*   ecb    = (const int*)d_in[21];
    float* out = (float*)d_out;

    char* w = (char*)d_ws;
    u16*   s1h  = (u16*)w;                          // 15,728,640
    u16*   qkvb = (u16*)(w + 15728640);             // 47,185,920 ; act aliases
    u16*   act  = qkvb;                             // (dead after k_attn)
    u16*   obuf = (u16*)(w + 62914560);             // 15,728,640
    u16*   r1h  = (u16*)(w + 78643200);             // 15,728,640
    u16*   hbuf = (u16*)(w + 94371840);             // 15,728,640
    u16*   mlph = (u16*)(w + 110100480);            // 15,728,640
    u16*   wq   = (u16*)(w + 125829120);            // 49152 u16
    u16*   wp   = wq + 384 * 128;                   // 16384 u16
    u16*   wg   = wp + 128 * 128;                   // 81920 u16
    u16*   wo   = wg + 640 * 128;                   // 40960 u16
    float* csum = (float*)(w + 125829120 + 376832);

    k_cvt<<<(188416 + 255) / 256, 256, 0, stream>>>(qkv_w, proj_w, glu_w, out_w, wq, wp, wg, wo);
    hipMemsetAsync(csum, 0, 8 * CH * sizeof(float), stream);

    k_ln1 <<<N_WIN * PW / 8, 256, 0, stream>>>(x, n1g, n1b, out);
    k_ln2a<<<NTOK / 8, 256, 0, stream>>>(out, n2g, n2b, iw, s1h);
    k_qkv <<<dim3(NTOK / 64, 3), 256, 0, stream>>>(s1h, wq, qkv_b, qkvb);
    k_attn<<<MSEL, 256, 0, stream>>>(qkvb, obuf);
    k_proj<<<NTOK / 64, 256, 0, stream>>>(obuf, wp, proj_b, s1h, ls1, n2g, n2b, r1h, hbuf);
    k_glu <<<dim3(NTOK / 64, 5), 256, 0, stream>>>(hbuf, wg, glu_b, act);
    k_out <<<dim3(NTOK / 64, 2), 256, 0, stream>>>(act, wo, out_b, mlph);
    k_csum<<<NTOK / 256, 256, 0, stream>>>(mlph, iw, csum);
    k_final<<<(NTOK * CH / 8) / 256, 256, 0, stream>>>(r1h, mlph, csum, ls2, iw, ecb, out);
    (void)in_sizes; (void)n_in; (void)out_size; (void)ws_size;
}